// Round 4
// baseline (719.969 us; speedup 1.0000x reference)
//
#include <hip/hip_runtime.h>

#define NN 1000
#define NE 64000
#define HH 256

typedef _Float16 half8 __attribute__((ext_vector_type(8)));
typedef float floatx4 __attribute__((ext_vector_type(4)));

struct PrepArgs { const float* w0[5]; const float* w1[5]; };

// ---------------------------------------------------------------------------
// Pipeline (7 dispatches; boundary tax measured ~6-7 µs each on 8 XCDs):
//   1. k_prep  : zero counts/cursor/dcnt/aggA; swizzle weights to fragment order
//   2. k_pre   : hist (4 blks) || layer-0 node GEMM (252 blks)
//                -> flag barrier -> replicated scan + counting-sort scatter
//   3-6. k_layer : edge GEMM+scatter-max (1000 blks) -> zero agg_next
//                -> flag barrier (only 252 blks spin) -> node GEMM layer l+1
//   7. k_last  : edge GEMM + exact-fp32 interior-run epilogue -> d_out
// Flag barrier = minimal coherence: writers __threadfence (buffer_wbl2 of own
// dirty agg lines) + one agent fetch_add; readers relaxed spin + acquire
// fence (buffer_inv; they hold no stale lines). NOT cg::grid.sync (round-1:
// ~110 µs/sync). Co-residency: 33 KB LDS -> 4 blk/CU -> 1024 >= 1000 blocks.
// ---------------------------------------------------------------------------

__global__ __launch_bounds__(256) void k_prep(PrepArgs pa,
                                              _Float16* wnode, _Float16* w2h,
                                              int* counts, int* cursor,
                                              int* dcnt, float* aggA) {
    int gtid = blockIdx.x * 256 + threadIdx.x;
    int gstride = gridDim.x * 256;
    for (int i = gtid; i < 1024; i += gstride) { counts[i] = 0; cursor[i] = 0; dcnt[i] = 0; }
    for (int l = 0; l < 5; l++) {
        const int KK = l ? 8 : 4;
        const int D = KK * 32;
        const int lgKK = l ? 3 : 2;
        const float* w0 = pa.w0[l];
        _Float16* wn = wnode + l * 131072;
        for (int i = gtid; i < 16384 * KK; i += gstride) {
            int j = i & 7;
            int lane = (i >> 3) & 63;
            int nt = (i >> 9) & 1;
            int kk = (i >> 10) & (KK - 1);
            int slice = i >> (10 + lgKK);
            int mn = lane & 15, q = lane >> 4;
            int n = slice * 32 + nt * 16 + mn;
            int k = kk * 32 + q * 8 + j;
            float v = (n < 256) ? (w0[n * 2 * D + k] - w0[n * 2 * D + D + k])
                                : w0[(n - 256) * 2 * D + D + k];
            wn[i] = (_Float16)v;
        }
        const float* w1 = pa.w1[l];
        _Float16* w2 = w2h + l * 65536;
        for (int i = gtid; i < 65536; i += gstride) {
            int j = i & 7;
            int lane = (i >> 3) & 63;
            int nt = (i >> 9) & 3;
            int kk = (i >> 11) & 7;
            int ws = (i >> 14) & 3;
            int mn = lane & 15, q = lane >> 4;
            int row = ws * 64 + nt * 16 + mn;
            int col = kk * 32 + q * 8 + j;
            w2[i] = (_Float16)w1[row * 256 + col];
        }
    }
    floatx4 z = {0.f, 0.f, 0.f, 0.f};
    floatx4* p4 = (floatx4*)aggA;
    for (int i = gtid; i < NN * HH / 4; i += gstride) p4[i] = z;
}

// C = X[M,Kd] @ Wn^T, 16x128 tile (252 tiles); Wn fragment order.
// Interleaved load+MFMA (low VGPR -- fits under launch_bounds(256,4) cap).
template <int NK>
__device__ __forceinline__ void node_tile(const float* __restrict__ X,
                                          const _Float16* __restrict__ Wn,
                                          const float* __restrict__ b0,
                                          _Float16* out, int bid) {
    const int Kd = NK * 32;
    int t = threadIdx.x;
    int wave = t >> 6, lane = t & 63;
    int q = lane >> 4, mn = lane & 15;
    int m0 = (bid % 63) * 16;
    int n0 = (bid / 63) * 128 + wave * 32;
    int slice = (bid / 63) * 4 + wave;
    int rr = m0 + mn;
    if (rr >= NN) rr = NN - 1;
    floatx4 acc[2] = {};
#pragma unroll
    for (int kk = 0; kk < NK; kk++) {
        int ka = kk * 32 + q * 8;
        const float* p = X + (size_t)rr * Kd + ka;
        floatx4 x0 = *(const floatx4*)p;
        floatx4 x1 = *(const floatx4*)(p + 4);
        half8 aa;
#pragma unroll
        for (int j = 0; j < 4; j++) { aa[j] = (_Float16)x0[j]; aa[4 + j] = (_Float16)x1[j]; }
        half8 bf0 = *(const half8*)(Wn + (((slice * NK + kk) * 2 + 0) * 64 + lane) * 8);
        half8 bf1 = *(const half8*)(Wn + (((slice * NK + kk) * 2 + 1) * 64 + lane) * 8);
        acc[0] = __builtin_amdgcn_mfma_f32_16x16x32_f16(aa, bf0, acc[0], 0, 0, 0);
        acc[1] = __builtin_amdgcn_mfma_f32_16x16x32_f16(aa, bf1, acc[1], 0, 0, 0);
    }
#pragma unroll
    for (int nt = 0; nt < 2; nt++) {
        int col = n0 + nt * 16 + mn;
        float bias = (col < 256) ? b0[col] : 0.f;
#pragma unroll
        for (int r2 = 0; r2 < 4; r2++) {
            int orow = m0 + q * 4 + r2;
            if (orow < NN)
                out[(size_t)orow * 512 + col] = (_Float16)(acc[nt][r2] + bias);
        }
    }
}

__device__ __forceinline__ void barrier_arrive(int* dcnt) {
    __threadfence();                 // buffer_wbl2: my dirty lines -> LLC
    __syncthreads();
    if (threadIdx.x == 0)
        __hip_atomic_fetch_add(dcnt, 1, __ATOMIC_ACQ_REL, __HIP_MEMORY_SCOPE_AGENT);
}

__device__ __forceinline__ void barrier_wait(int* dcnt, int target) {
    if (threadIdx.x == 0)
        while (__hip_atomic_load(dcnt, __ATOMIC_RELAXED, __HIP_MEMORY_SCOPE_AGENT) < target)
            __builtin_amdgcn_s_sleep(1);
    __syncthreads();
    __threadfence();                 // buffer_inv: subsequent reads see LLC
}

// hist (4 blocks) || layer-0 node GEMM (252) -> barrier -> scan + scatter
__global__ __launch_bounds__(256) void k_pre(const int* __restrict__ ei,
                                             int* __restrict__ counts,
                                             int* __restrict__ cursor,
                                             const float* __restrict__ X,
                                             const _Float16* __restrict__ Wn,
                                             const float* __restrict__ b0,
                                             _Float16* nab,
                                             int* __restrict__ ssrc,
                                             int* __restrict__ sdst,
                                             int* dcnt) {
    __shared__ int sbase[1024];
    __shared__ int ssum[256];
    int bid = blockIdx.x, t = threadIdx.x;
    if (bid < 4) {
        for (int e = bid * 256 + t; e < NE; e += 4 * 256)
            atomicAdd(&counts[ei[NE + e] & 1023], 1);
    } else {
        node_tile<4>(X, Wn, b0, nab, bid - 4);
    }
    barrier_arrive(dcnt);
    barrier_wait(dcnt, 256);

    int base = t * 4;
    int c4[4]; int sum = 0;
#pragma unroll
    for (int j = 0; j < 4; j++) { c4[j] = counts[base + j]; sum += c4[j]; }
    ssum[t] = sum;
    __syncthreads();
    for (int d = 1; d < 256; d <<= 1) {
        int v = (t >= d) ? ssum[t - d] : 0;
        __syncthreads();
        ssum[t] += v;
        __syncthreads();
    }
    int run = (t > 0) ? ssum[t - 1] : 0;
#pragma unroll
    for (int j = 0; j < 4; j++) { sbase[base + j] = run; run += c4[j]; }
    __syncthreads();
    for (int e = bid * 256 + t; e < NE; e += gridDim.x * 256) {
        int s = ei[e] & 1023, d = ei[NE + e] & 1023;
        int pos = sbase[d] + atomicAdd(&cursor[d], 1);
        if (pos < NE) { ssrc[pos] = s; sdst[pos] = d; }
    }
}

// 64 sorted edges x 256 cols: stage h1 = relu(a[dst]+b[src]) XOR-swizzled in
// LDS, MFMA vs fragment-ordered W2 -> acc[4][4]. (Verified round-0/3 body.)
__device__ __forceinline__ void edge_mfma(const _Float16* node_ab,
                                          const int* __restrict__ ssrc,
                                          const int* __restrict__ sdst,
                                          const _Float16* __restrict__ W2,
                                          int tile, _Float16* h1, int* sd,
                                          floatx4 acc[4][4]) {
    int t = threadIdx.x;
    int e0 = tile * 64;
    int wave = t >> 6, lane = t & 63;
    int q = lane >> 4, mn = lane & 15;
    const _Float16* W2w = W2 + wave * 16384;

    if (t < 64) sd[t] = sdst[e0 + t];
    {
        int row = t & 63;
        int cb = (t >> 6) * 8;
        int dn = sdst[e0 + row], sn = ssrc[e0 + row];
        const _Float16* pa = node_ab + (size_t)dn * 512 + cb * 8;
        const _Float16* pb = node_ab + (size_t)sn * 512 + 256 + cb * 8;
        half8 av[8], bv[8];
#pragma unroll
        for (int i = 0; i < 8; i++) av[i] = *(const half8*)(pa + i * 8);
#pragma unroll
        for (int i = 0; i < 8; i++) bv[i] = *(const half8*)(pb + i * 8);
#pragma unroll
        for (int i = 0; i < 8; i++) {
            int c = cb + i;
            int p = (c & ~7) | ((c ^ row) & 7);
            half8 hv = av[i] + bv[i];
#pragma unroll
            for (int j = 0; j < 8; j++) hv[j] = hv[j] > (_Float16)0 ? hv[j] : (_Float16)0;
            *(half8*)(&h1[row * 256 + p * 8]) = hv;
        }
    }
    __syncthreads();

#pragma unroll
    for (int kk = 0; kk < 8; kk++) {
        half8 bf[4];
#pragma unroll
        for (int nt = 0; nt < 4; nt++)
            bf[nt] = *(const half8*)(W2w + (kk * 4 + nt) * 512 + lane * 8);
        half8 af[4];
#pragma unroll
        for (int mt = 0; mt < 4; mt++) {
            int r = mt * 16 + mn;
            int c = kk * 4 + q;
            int p = (c & ~7) | ((c ^ r) & 7);
            af[mt] = *(const half8*)(&h1[r * 256 + p * 8]);
        }
#pragma unroll
        for (int mt = 0; mt < 4; mt++)
#pragma unroll
            for (int nt = 0; nt < 4; nt++)
                acc[mt][nt] = __builtin_amdgcn_mfma_f32_16x16x32_f16(af[mt], bf[nt], acc[mt][nt], 0, 0, 0);
    }
}

// edge layer l (1000 blocks, 1 tile each) -> zero agg_next -> flag barrier ->
// 252 blocks: node GEMM layer l+1. Co-residency guaranteed (4 blk/CU x 256).
__global__ __launch_bounds__(256, 4) void k_layer(
        const _Float16* node_ab,
        const int* __restrict__ ssrc, const int* __restrict__ sdst,
        const _Float16* __restrict__ W2, const float* __restrict__ b2,
        float* __restrict__ agg, float* __restrict__ aggN,
        const _Float16* __restrict__ WnN, const float* __restrict__ b0N,
        int* dcnt) {
    __shared__ _Float16 h1[64 * 256];
    __shared__ int sd[64];
    int bid = blockIdx.x, t = threadIdx.x;
    int wave = t >> 6, lane = t & 63;
    int q = lane >> 4, mn = lane & 15;

    floatx4 acc[4][4] = {};
    edge_mfma(node_ab, ssrc, sdst, W2, bid, h1, sd, acc);

    __syncthreads();  // h1 fragment reads done before overwrite
    // h2 = relu(acc+bias) -> h1 (fp16, same XOR swizzle at 8-half granularity)
#pragma unroll
    for (int nt = 0; nt < 4; nt++) {
        int col = wave * 64 + nt * 16 + mn;
        float bias = b2[col];
        int g = col >> 3, o = col & 7;
#pragma unroll
        for (int mt = 0; mt < 4; mt++) {
#pragma unroll
            for (int r2 = 0; r2 < 4; r2++) {
                int row = mt * 16 + q * 4 + r2;
                float v = acc[mt][nt][r2] + bias;
                v = v > 0.f ? v : 0.f;
                int pg = (g & ~7) | ((g ^ row) & 7);
                h1[row * 256 + pg * 8 + o] = (_Float16)v;
            }
        }
    }
    __syncthreads();

    // column-owner run scan: interior runs -> plain store (block-exclusive);
    // boundary runs -> atomicMax. agg pre-zeroed.
    {
        int c = t;
        int g = c >> 3, o = c & 7;
        float* aggc = agg + c;
        float m = (float)h1[g * 8 + o];
        bool sedge = true;
        int prevd = sd[0];
#pragma unroll 8
        for (int r = 1; r < 64; r++) {
            int d = sd[r];
            int pg = (g & ~7) | ((g ^ r) & 7);
            float v = (float)h1[r * 256 + pg * 8 + o];
            if (d != prevd) {
                if (sedge) {
                    if (m > 0.f)
                        atomicMax((unsigned int*)(aggc + (size_t)prevd * HH), __float_as_uint(m));
                } else {
                    if (m > 0.f)
                        aggc[(size_t)prevd * HH] = m;
                }
                m = v; sedge = false; prevd = d;
            } else {
                m = fmaxf(m, v);
            }
        }
        if (m > 0.f)
            atomicMax((unsigned int*)(aggc + (size_t)prevd * HH), __float_as_uint(m));
    }

    // zero next layer's agg (read only by NEXT dispatch -> boundary handles)
    if (bid >= 252) {
        floatx4 z = {0.f, 0.f, 0.f, 0.f};
        floatx4* p4 = (floatx4*)aggN;
        for (int i = (bid - 252) * 256 + t; i < NN * HH / 4; i += 748 * 256)
            p4[i] = z;
    }

    barrier_arrive(dcnt);
    if (bid < 252) {
        barrier_wait(dcnt, 1000);
        node_tile<8>(agg, WnN, b0N, (_Float16*)node_ab, bid);
    }
}

// last layer: edge GEMM + exact-fp32 interior-run epilogue (two passes of 128
// cols through padded-stride LDS -> no fp16 rounding of d_out, numerics
// identical to the atomic baseline; max is exact in fp32).
__global__ __launch_bounds__(256, 4) void k_last(
        const _Float16* __restrict__ node_ab,
        const int* __restrict__ ssrc, const int* __restrict__ sdst,
        const _Float16* __restrict__ W2, const float* __restrict__ b2,
        float* __restrict__ agg) {
    __shared__ float sf[64 * 129];   // 33 KB; stride 129 -> conflict-free scan
    __shared__ int sd[64];
    _Float16* h1 = (_Float16*)sf;    // 32 KB alias for the staging/MFMA phase
    int t = threadIdx.x;
    int wave = t >> 6, lane = t & 63;
    int q = lane >> 4, mn = lane & 15;

    floatx4 acc[4][4] = {};
    edge_mfma(node_ab, ssrc, sdst, W2, blockIdx.x, h1, sd, acc);

    __syncthreads();  // h1 reads done
#pragma unroll
    for (int p = 0; p < 2; p++) {
        if (p) __syncthreads();      // pass-0 scan done before rewrite
        if ((wave >> 1) == p) {
            int lc0 = (wave & 1) * 64;
#pragma unroll
            for (int nt = 0; nt < 4; nt++) {
                int col = wave * 64 + nt * 16 + mn;
                float bias = b2[col];
                int lc = lc0 + nt * 16 + mn;
#pragma unroll
                for (int mt = 0; mt < 4; mt++) {
#pragma unroll
                    for (int r2 = 0; r2 < 4; r2++) {
                        int row = mt * 16 + q * 4 + r2;
                        float v = acc[mt][nt][r2] + bias;
                        sf[row * 129 + lc] = v > 0.f ? v : 0.f;
                    }
                }
            }
        }
        __syncthreads();
        if (t < 128) {
            float* aggc = agg + p * 128 + t;
            float m = sf[t];
            bool sedge = true;
            int prevd = sd[0];
#pragma unroll 8
            for (int r = 1; r < 64; r++) {
                int d = sd[r];
                float v = sf[r * 129 + t];
                if (d != prevd) {
                    if (sedge) {
                        if (m > 0.f)
                            atomicMax((unsigned int*)(aggc + (size_t)prevd * HH), __float_as_uint(m));
                    } else {
                        if (m > 0.f)
                            aggc[(size_t)prevd * HH] = m;
                    }
                    m = v; sedge = false; prevd = d;
                } else {
                    m = fmaxf(m, v);
                }
            }
            if (m > 0.f)
                atomicMax((unsigned int*)(aggc + (size_t)prevd * HH), __float_as_uint(m));
        }
    }
}

extern "C" void kernel_launch(void* const* d_in, const int* in_sizes, int n_in,
                              void* d_out, int out_size, void* d_ws, size_t ws_size,
                              hipStream_t stream) {
    const float* x = (const float*)d_in[0];
    const int* ei = (const int*)d_in[1];  // int32 per harness contract
    PrepArgs pa;
    const float* b0s[5];
    const float* b1s[5];
    for (int l = 0; l < 5; l++) {
        pa.w0[l] = (const float*)d_in[2 + 4 * l];
        b0s[l] = (const float*)d_in[3 + 4 * l];
        pa.w1[l] = (const float*)d_in[4 + 4 * l];
        b1s[l] = (const float*)d_in[5 + 4 * l];
    }

    int* ssrc = (int*)d_ws;                              // 256 KB
    int* sdst = ssrc + NE;                               // 256 KB
    int* counts = sdst + NE;                             // 4 KB
    int* cursor = counts + 1024;                         // 4 KB
    int* dcnt = cursor + 1024;                           // 4 KB (barrier flags)
    _Float16* node_ab = (_Float16*)(dcnt + 1024);        // [1024][512] fp16, 1 MB
    float* aggA = (float*)(node_ab + 1024 * 512);        // 1 MB
    float* aggB = aggA + NN * HH;                        // 1 MB
    _Float16* wnode = (_Float16*)(aggB + NN * HH);       // 5 x 131072 halfs
    _Float16* w2h = wnode + 5 * 131072;                  // 5 x 65536 halfs

    hipLaunchKernelGGL(k_prep, dim3(256), dim3(256), 0, stream,
                       pa, wnode, w2h, counts, cursor, dcnt, aggA);
    hipLaunchKernelGGL(k_pre, dim3(256), dim3(256), 0, stream,
                       ei, counts, cursor, x, wnode, b0s[0], node_ab,
                       ssrc, sdst, dcnt + 512);

    float* aggs[5] = {aggA, aggB, aggA, aggB, (float*)d_out};
    for (int l = 0; l < 4; l++) {
        hipLaunchKernelGGL(k_layer, dim3(NE / 64), dim3(256), 0, stream,
                           node_ab, ssrc, sdst, w2h + (size_t)l * 65536, b1s[l],
                           aggs[l], aggs[l + 1],
                           wnode + (size_t)(l + 1) * 131072, b0s[l + 1],
                           dcnt + l * 32);
    }
    hipLaunchKernelGGL(k_last, dim3(NE / 64), dim3(256), 0, stream,
                       node_ab, ssrc, sdst, w2h + (size_t)4 * 65536, b1s[4],
                       (float*)d_out);
}

// Round 7
// 271.903 us; speedup vs baseline: 2.6479x; 2.6479x over previous
//
#include <hip/hip_runtime.h>

#define NN 1000
#define NE 64000
#define HH 256

typedef _Float16 half8 __attribute__((ext_vector_type(8)));
typedef float floatx4 __attribute__((ext_vector_type(4)));

struct PrepArgs { const float* w0[5]; const float* w1[5]; };

// ---------------------------------------------------------------------------
// Pipeline (12 dispatches; boundary ~2 µs each — measured round-2 accounting.
// In-kernel cross-block sync is BANNED: grid.sync ~110 µs (r1), flag-barrier
// +threadfence ~115 µs (r4) — buffer_wbl2 is a whole-L2 writeback).
//   1. k_prep      : swizzle weights; zero counts/cursor + ALL 4 agg buffers
//                    + d_out (moves zero chores off the critical path)
//   2. k_hist_node0: dst histogram (4 blks) + layer-0 node GEMM (252 blks)
//   3. k_scatter2  : per-block replicated prefix scan + counting-sort scatter
//   4..11. 4 x (edge_gemm2 + k_node), 12. edge_last
// edge epilogue: sorted-by-dst edges => interior dst runs are block-exclusive
// => plain store; only runs touching tile row 0/63 need device atomicMax
// (~70 vs ~2048 per block). Last layer: exact-fp32 two-pass variant (no fp16
// rounding of d_out; max exact in fp32 -> numerics identical to baseline).
// ---------------------------------------------------------------------------

__global__ __launch_bounds__(256) void k_prep(PrepArgs pa,
                                              _Float16* wnode, _Float16* w2h,
                                              int* counts, int* cursor,
                                              float* agg0, float* out) {
    int gtid = blockIdx.x * 256 + threadIdx.x;
    int gstride = gridDim.x * 256;
    for (int i = gtid; i < 1024; i += gstride) { counts[i] = 0; cursor[i] = 0; }
    for (int l = 0; l < 5; l++) {
        const int KK = l ? 8 : 4;
        const int D = KK * 32;
        const int lgKK = l ? 3 : 2;
        const float* w0 = pa.w0[l];
        _Float16* wn = wnode + l * 131072;
        for (int i = gtid; i < 16384 * KK; i += gstride) {
            int j = i & 7;
            int lane = (i >> 3) & 63;
            int nt = (i >> 9) & 1;
            int kk = (i >> 10) & (KK - 1);
            int slice = i >> (10 + lgKK);
            int mn = lane & 15, q = lane >> 4;
            int n = slice * 32 + nt * 16 + mn;
            int k = kk * 32 + q * 8 + j;
            float v = (n < 256) ? (w0[n * 2 * D + k] - w0[n * 2 * D + D + k])
                                : w0[(n - 256) * 2 * D + D + k];
            wn[i] = (_Float16)v;
        }
        const float* w1 = pa.w1[l];
        _Float16* w2 = w2h + l * 65536;
        for (int i = gtid; i < 65536; i += gstride) {
            int j = i & 7;
            int lane = (i >> 3) & 63;
            int nt = (i >> 9) & 3;
            int kk = (i >> 11) & 7;
            int ws = (i >> 14) & 3;
            int mn = lane & 15, q = lane >> 4;
            int row = ws * 64 + nt * 16 + mn;
            int col = kk * 32 + q * 8 + j;
            w2[i] = (_Float16)w1[row * 256 + col];
        }
    }
    // zero agg0..agg3 (contiguous 4 x NN*HH floats) and d_out
    floatx4 z = {0.f, 0.f, 0.f, 0.f};
    floatx4* p4 = (floatx4*)agg0;
    for (int i = gtid; i < 4 * NN * HH / 4; i += gstride) p4[i] = z;
    floatx4* o4 = (floatx4*)out;
    for (int i = gtid; i < NN * HH / 4; i += gstride) o4[i] = z;
}

// C = X[M,Kd] @ Wn^T, 16x128 tile per block (252 tiles); Wn in fragment order.
template <int NK>
__device__ __forceinline__ void node_tile(const float* __restrict__ X,
                                          const _Float16* __restrict__ Wn,
                                          const float* __restrict__ b0,
                                          _Float16* __restrict__ out, int bid) {
    const int Kd = NK * 32;
    int t = threadIdx.x;
    int wave = t >> 6, lane = t & 63;
    int q = lane >> 4, mn = lane & 15;
    int m0 = (bid % 63) * 16;
    int n0 = (bid / 63) * 128 + wave * 32;
    int slice = (bid / 63) * 4 + wave;
    int rr = m0 + mn;
    if (rr >= NN) rr = NN - 1;

    half8 afa[NK];
    half8 bfa[NK][2];
#pragma unroll
    for (int kk = 0; kk < NK; kk++) {
        int ka = kk * 32 + q * 8;
        const float* p = X + (size_t)rr * Kd + ka;
        floatx4 x0 = *(const floatx4*)p;
        floatx4 x1 = *(const floatx4*)(p + 4);
        half8 aa;
#pragma unroll
        for (int j = 0; j < 4; j++) { aa[j] = (_Float16)x0[j]; aa[4 + j] = (_Float16)x1[j]; }
        afa[kk] = aa;
        bfa[kk][0] = *(const half8*)(Wn + (((slice * NK + kk) * 2 + 0) * 64 + lane) * 8);
        bfa[kk][1] = *(const half8*)(Wn + (((slice * NK + kk) * 2 + 1) * 64 + lane) * 8);
    }
    floatx4 acc[2] = {};
#pragma unroll
    for (int kk = 0; kk < NK; kk++) {
        acc[0] = __builtin_amdgcn_mfma_f32_16x16x32_f16(afa[kk], bfa[kk][0], acc[0], 0, 0, 0);
        acc[1] = __builtin_amdgcn_mfma_f32_16x16x32_f16(afa[kk], bfa[kk][1], acc[1], 0, 0, 0);
    }
#pragma unroll
    for (int nt = 0; nt < 2; nt++) {
        int col = n0 + nt * 16 + mn;
        float bias = (col < 256) ? b0[col] : 0.f;
#pragma unroll
        for (int r2 = 0; r2 < 4; r2++) {
            int orow = m0 + q * 4 + r2;
            if (orow < NN)
                out[(size_t)orow * 512 + col] = (_Float16)(acc[nt][r2] + bias);
        }
    }
}

// blocks 0..3: dst histogram; blocks 4..255: layer-0 node GEMM
__global__ __launch_bounds__(256) void k_hist_node0(const int* __restrict__ ei,
                                                    int* __restrict__ counts,
                                                    const float* __restrict__ X,
                                                    const _Float16* __restrict__ Wn,
                                                    const float* __restrict__ b0,
                                                    _Float16* __restrict__ out) {
    int bid = blockIdx.x;
    if (bid < 4) {
        for (int e = bid * 256 + threadIdx.x; e < NE; e += 4 * 256)
            atomicAdd(&counts[ei[NE + e] & 1023], 1);
    } else {
        node_tile<4>(X, Wn, b0, out, bid - 4);
    }
}

// Per-block replicated exclusive scan, then counting-sort scatter by dst.
__global__ __launch_bounds__(256) void k_scatter2(const int* __restrict__ ei,
                                                  const int* __restrict__ counts,
                                                  int* __restrict__ cursor,
                                                  int* __restrict__ ssrc,
                                                  int* __restrict__ sdst) {
    __shared__ int sbase[1024];
    __shared__ int ssum[256];
    int t = threadIdx.x;
    int base = t * 4;
    int c4[4]; int sum = 0;
#pragma unroll
    for (int j = 0; j < 4; j++) { c4[j] = counts[base + j]; sum += c4[j]; }
    ssum[t] = sum;
    __syncthreads();
    for (int d = 1; d < 256; d <<= 1) {
        int v = (t >= d) ? ssum[t - d] : 0;
        __syncthreads();
        ssum[t] += v;
        __syncthreads();
    }
    int run = (t > 0) ? ssum[t - 1] : 0;
#pragma unroll
    for (int j = 0; j < 4; j++) { sbase[base + j] = run; run += c4[j]; }
    __syncthreads();
    for (int e = blockIdx.x * 256 + t; e < NE; e += gridDim.x * 256) {
        int s = ei[e] & 1023, d = ei[NE + e] & 1023;
        int pos = sbase[d] + atomicAdd(&cursor[d], 1);
        if (pos < NE) { ssrc[pos] = s; sdst[pos] = d; }
    }
}

// pure node GEMM layer l+1 (reads agg_in), 252 blocks
__global__ __launch_bounds__(256) void k_node(const float* __restrict__ agg_in,
                                              const _Float16* __restrict__ Wn,
                                              const float* __restrict__ b0,
                                              _Float16* __restrict__ out) {
    node_tile<8>(agg_in, Wn, b0, out, blockIdx.x);
}

// 64 sorted edges x 256 cols: stage h1 = relu(a[dst]+b[src]) XOR-swizzled in
// LDS, MFMA vs fragment-ordered W2 -> acc[4][4]. (Verified r0/r3 body.)
__device__ __forceinline__ void edge_mfma(const _Float16* __restrict__ node_ab,
                                          const int* __restrict__ ssrc,
                                          const int* __restrict__ sdst,
                                          const _Float16* __restrict__ W2,
                                          int tile, _Float16* h1, int* sd,
                                          floatx4 acc[4][4]) {
    int t = threadIdx.x;
    int e0 = tile * 64;
    int wave = t >> 6, lane = t & 63;
    int q = lane >> 4, mn = lane & 15;
    const _Float16* W2w = W2 + wave * 16384;

    if (t < 64) sd[t] = sdst[e0 + t];
    {
        int row = t & 63;
        int cb = (t >> 6) * 8;
        int dn = sdst[e0 + row], sn = ssrc[e0 + row];
        const _Float16* pa = node_ab + (size_t)dn * 512 + cb * 8;
        const _Float16* pb = node_ab + (size_t)sn * 512 + 256 + cb * 8;
        half8 av[8], bv[8];
#pragma unroll
        for (int i = 0; i < 8; i++) av[i] = *(const half8*)(pa + i * 8);
#pragma unroll
        for (int i = 0; i < 8; i++) bv[i] = *(const half8*)(pb + i * 8);
#pragma unroll
        for (int i = 0; i < 8; i++) {
            int c = cb + i;
            int p = (c & ~7) | ((c ^ row) & 7);
            half8 hv = av[i] + bv[i];
#pragma unroll
            for (int j = 0; j < 8; j++) hv[j] = hv[j] > (_Float16)0 ? hv[j] : (_Float16)0;
            *(half8*)(&h1[row * 256 + p * 8]) = hv;
        }
    }
    __syncthreads();

#pragma unroll
    for (int kk = 0; kk < 8; kk++) {
        half8 bf[4];
#pragma unroll
        for (int nt = 0; nt < 4; nt++)
            bf[nt] = *(const half8*)(W2w + (kk * 4 + nt) * 512 + lane * 8);  // coalesced
        half8 af[4];
#pragma unroll
        for (int mt = 0; mt < 4; mt++) {
            int r = mt * 16 + mn;
            int c = kk * 4 + q;
            int p = (c & ~7) | ((c ^ r) & 7);
            af[mt] = *(const half8*)(&h1[r * 256 + p * 8]);
        }
#pragma unroll
        for (int mt = 0; mt < 4; mt++)
#pragma unroll
            for (int nt = 0; nt < 4; nt++)
                acc[mt][nt] = __builtin_amdgcn_mfma_f32_16x16x32_f16(af[mt], bf[nt], acc[mt][nt], 0, 0, 0);
    }
}

// middle layers: h2=relu(acc+bias) -> fp16 LDS (same swizzle), column-owner
// run scan; interior runs plain-store, boundary runs atomicMax. agg pre-zeroed.
__global__ __launch_bounds__(256, 4) void edge_gemm2(const _Float16* __restrict__ node_ab,
                          const int* __restrict__ ssrc, const int* __restrict__ sdst,
                          const _Float16* __restrict__ W2, const float* __restrict__ b2,
                          float* __restrict__ agg) {
    __shared__ _Float16 h1[64 * 256];
    __shared__ int sd[64];
    int t = threadIdx.x;
    int wave = t >> 6, lane = t & 63;
    int q = lane >> 4, mn = lane & 15;

    floatx4 acc[4][4] = {};
    edge_mfma(node_ab, ssrc, sdst, W2, blockIdx.x, h1, sd, acc);

    __syncthreads();  // all h1 fragment reads done before overwrite
#pragma unroll
    for (int nt = 0; nt < 4; nt++) {
        int col = wave * 64 + nt * 16 + mn;
        float bias = b2[col];
        int g = col >> 3, o = col & 7;
#pragma unroll
        for (int mt = 0; mt < 4; mt++) {
#pragma unroll
            for (int r2 = 0; r2 < 4; r2++) {
                int row = mt * 16 + q * 4 + r2;
                float v = acc[mt][nt][r2] + bias;
                v = v > 0.f ? v : 0.f;
                int pg = (g & ~7) | ((g ^ row) & 7);
                h1[row * 256 + pg * 8 + o] = (_Float16)v;
            }
        }
    }
    __syncthreads();

    {
        int c = t;
        int g = c >> 3, o = c & 7;
        float* aggc = agg + c;
        float m = (float)h1[g * 8 + o];  // row 0: pg = g
        bool sedge = true;
        int prevd = sd[0];
#pragma unroll 8
        for (int r = 1; r < 64; r++) {
            int d = sd[r];
            int pg = (g & ~7) | ((g ^ r) & 7);
            float v = (float)h1[r * 256 + pg * 8 + o];
            if (d != prevd) {
                if (sedge) {
                    if (m > 0.f)
                        atomicMax((unsigned int*)(aggc + (size_t)prevd * HH), __float_as_uint(m));
                } else {
                    if (m > 0.f)
                        aggc[(size_t)prevd * HH] = m;   // block-exclusive
                }
                m = v; sedge = false; prevd = d;
            } else {
                m = fmaxf(m, v);
            }
        }
        if (m > 0.f)
            atomicMax((unsigned int*)(aggc + (size_t)prevd * HH), __float_as_uint(m));
    }
}

// last layer: exact-fp32 two-pass epilogue (padded-stride LDS transpose;
// interior runs plain-store; d_out numerics identical to atomic baseline).
__global__ __launch_bounds__(256, 4) void edge_last(
        const _Float16* __restrict__ node_ab,
        const int* __restrict__ ssrc, const int* __restrict__ sdst,
        const _Float16* __restrict__ W2, const float* __restrict__ b2,
        float* __restrict__ agg) {
    __shared__ float sf[64 * 129];   // 33 KB; stride 129 -> conflict-free scan
    __shared__ int sd[64];
    _Float16* h1 = (_Float16*)sf;    // 32 KB alias for the staging/MFMA phase
    int t = threadIdx.x;
    int wave = t >> 6, lane = t & 63;
    int q = lane >> 4, mn = lane & 15;

    floatx4 acc[4][4] = {};
    edge_mfma(node_ab, ssrc, sdst, W2, blockIdx.x, h1, sd, acc);

    __syncthreads();  // h1 reads done
#pragma unroll
    for (int p = 0; p < 2; p++) {
        if (p) __syncthreads();      // pass-0 scan done before rewrite
        if ((wave >> 1) == p) {
            int lc0 = (wave & 1) * 64;
#pragma unroll
            for (int nt = 0; nt < 4; nt++) {
                int col = wave * 64 + nt * 16 + mn;
                float bias = b2[col];
                int lc = lc0 + nt * 16 + mn;
#pragma unroll
                for (int mt = 0; mt < 4; mt++) {
#pragma unroll
                    for (int r2 = 0; r2 < 4; r2++) {
                        int row = mt * 16 + q * 4 + r2;
                        float v = acc[mt][nt][r2] + bias;
                        sf[row * 129 + lc] = v > 0.f ? v : 0.f;
                    }
                }
            }
        }
        __syncthreads();
        if (t < 128) {
            float* aggc = agg + p * 128 + t;
            float m = sf[t];
            bool sedge = true;
            int prevd = sd[0];
#pragma unroll 8
            for (int r = 1; r < 64; r++) {
                int d = sd[r];
                float v = sf[r * 129 + t];
                if (d != prevd) {
                    if (sedge) {
                        if (m > 0.f)
                            atomicMax((unsigned int*)(aggc + (size_t)prevd * HH), __float_as_uint(m));
                    } else {
                        if (m > 0.f)
                            aggc[(size_t)prevd * HH] = m;
                    }
                    m = v; sedge = false; prevd = d;
                } else {
                    m = fmaxf(m, v);
                }
            }
            if (m > 0.f)
                atomicMax((unsigned int*)(aggc + (size_t)prevd * HH), __float_as_uint(m));
        }
    }
}

extern "C" void kernel_launch(void* const* d_in, const int* in_sizes, int n_in,
                              void* d_out, int out_size, void* d_ws, size_t ws_size,
                              hipStream_t stream) {
    const float* x = (const float*)d_in[0];
    const int* ei = (const int*)d_in[1];  // int32 per harness contract
    PrepArgs pa;
    const float* b0s[5];
    const float* b1s[5];
    for (int l = 0; l < 5; l++) {
        pa.w0[l] = (const float*)d_in[2 + 4 * l];
        b0s[l] = (const float*)d_in[3 + 4 * l];
        pa.w1[l] = (const float*)d_in[4 + 4 * l];
        b1s[l] = (const float*)d_in[5 + 4 * l];
    }

    int* ssrc = (int*)d_ws;                              // 256 KB
    int* sdst = ssrc + NE;                               // 256 KB
    int* counts = sdst + NE;                             // 4 KB
    int* cursor = counts + 1024;                         // 4 KB
    _Float16* node_ab = (_Float16*)(cursor + 1024);      // [1024][512] fp16, 1 MB
    float* agg0 = (float*)(node_ab + 1024 * 512);        // 4 x 1 MB (contiguous)
    float* agg1 = agg0 + NN * HH;
    float* agg2 = agg1 + NN * HH;
    float* agg3 = agg2 + NN * HH;
    _Float16* wnode = (_Float16*)(agg3 + NN * HH);       // 5 x 131072 halfs
    _Float16* w2h = wnode + 5 * 131072;                  // 5 x 65536 halfs

    hipLaunchKernelGGL(k_prep, dim3(256), dim3(256), 0, stream,
                       pa, wnode, w2h, counts, cursor, agg0, (float*)d_out);
    hipLaunchKernelGGL(k_hist_node0, dim3(256), dim3(256), 0, stream,
                       ei, counts, x, wnode, b0s[0], node_ab);
    hipLaunchKernelGGL(k_scatter2, dim3(NE / 256), dim3(256), 0, stream,
                       ei, counts, cursor, ssrc, sdst);

    float* aggs[4] = {agg0, agg1, agg2, agg3};
    for (int l = 0; l < 4; l++) {
        hipLaunchKernelGGL(edge_gemm2, dim3(NE / 64), dim3(256), 0, stream,
                           node_ab, ssrc, sdst, w2h + (size_t)l * 65536, b1s[l], aggs[l]);
        hipLaunchKernelGGL(k_node, dim3(252), dim3(256), 0, stream,
                           aggs[l], wnode + (size_t)(l + 1) * 131072, b0s[l + 1], node_ab);
    }
    hipLaunchKernelGGL(edge_last, dim3(NE / 64), dim3(256), 0, stream,
                       node_ab, ssrc, sdst, w2h + (size_t)4 * 65536, b1s[4],
                       (float*)d_out);
}

// Round 8
// 252.944 us; speedup vs baseline: 2.8464x; 1.0750x over previous
//
#include <hip/hip_runtime.h>

#define NN 1000
#define NE 64000
#define HH 256

typedef _Float16 half8 __attribute__((ext_vector_type(8)));
typedef float floatx4 __attribute__((ext_vector_type(4)));

struct PrepArgs { const float* w0[5]; const float* w1[5]; };

// ---------------------------------------------------------------------------
// Pipeline (11 dispatches; boundary ~2 µs. In-kernel cross-block sync BANNED:
// grid.sync ~110 µs (r1), threadfence flag-barrier ~115 µs (r4)).
//   1. k_pre1    : ONE dispatch, 524 independent blocks:
//                  blk 0..15   self-zeroed PRIVATE hist regions (16x1024)
//                  blk 16..267 layer-0 node GEMM, weights converted IN-KERNEL
//                              from w0[0] (drops the prep->node0 dependency)
//                  blk 268..523 chores: w2h + wnode(1..4) swizzle, zero
//                              cursor/agg0-3/d_out
//   2. k_scatter2: replicated scan (sums 16 regions) + counting-sort scatter
//   3..10. 4 x (edge_gemm2 + k_node), 11. edge_last
// edge epilogue: sorted-by-dst => interior runs block-exclusive => plain
// store; only runs touching tile row 0/63 use device atomicMax. Last layer:
// exact-fp32 two-pass epilogue (d_out numerics identical to baseline).
// ---------------------------------------------------------------------------

// C = X[M,Kd] @ Wn^T, 16x128 tile per block (252 tiles); Wn in fragment order.
template <int NK>
__device__ __forceinline__ void node_tile(const float* __restrict__ X,
                                          const _Float16* __restrict__ Wn,
                                          const float* __restrict__ b0,
                                          _Float16* __restrict__ out, int bid) {
    const int Kd = NK * 32;
    int t = threadIdx.x;
    int wave = t >> 6, lane = t & 63;
    int q = lane >> 4, mn = lane & 15;
    int m0 = (bid % 63) * 16;
    int n0 = (bid / 63) * 128 + wave * 32;
    int slice = (bid / 63) * 4 + wave;
    int rr = m0 + mn;
    if (rr >= NN) rr = NN - 1;

    half8 afa[NK];
    half8 bfa[NK][2];
#pragma unroll
    for (int kk = 0; kk < NK; kk++) {
        int ka = kk * 32 + q * 8;
        const float* p = X + (size_t)rr * Kd + ka;
        floatx4 x0 = *(const floatx4*)p;
        floatx4 x1 = *(const floatx4*)(p + 4);
        half8 aa;
#pragma unroll
        for (int j = 0; j < 4; j++) { aa[j] = (_Float16)x0[j]; aa[4 + j] = (_Float16)x1[j]; }
        afa[kk] = aa;
        bfa[kk][0] = *(const half8*)(Wn + (((slice * NK + kk) * 2 + 0) * 64 + lane) * 8);
        bfa[kk][1] = *(const half8*)(Wn + (((slice * NK + kk) * 2 + 1) * 64 + lane) * 8);
    }
    floatx4 acc[2] = {};
#pragma unroll
    for (int kk = 0; kk < NK; kk++) {
        acc[0] = __builtin_amdgcn_mfma_f32_16x16x32_f16(afa[kk], bfa[kk][0], acc[0], 0, 0, 0);
        acc[1] = __builtin_amdgcn_mfma_f32_16x16x32_f16(afa[kk], bfa[kk][1], acc[1], 0, 0, 0);
    }
#pragma unroll
    for (int nt = 0; nt < 2; nt++) {
        int col = n0 + nt * 16 + mn;
        float bias = (col < 256) ? b0[col] : 0.f;
#pragma unroll
        for (int r2 = 0; r2 < 4; r2++) {
            int orow = m0 + q * 4 + r2;
            if (orow < NN)
                out[(size_t)orow * 512 + col] = (_Float16)(acc[nt][r2] + bias);
        }
    }
}

// layer-0 node GEMM with IN-KERNEL fp32->fp16 fragment conversion from w0.
// Source row n = slice*32+nt*16+mn, cols k..k+7; n<256 -> (Wa-Wb), else Wb.
// (n<256) is uniform per (slice,nt) -> no lane divergence. Values identical
// to the old k_prep swizzle ((_Float16)(a-b) then MFMA).
__device__ __forceinline__ void node_tile0(const float* __restrict__ X,
                                           const float* __restrict__ w0,
                                           const float* __restrict__ b0,
                                           _Float16* __restrict__ out, int bid) {
    const int NK = 4;
    const int Kd = 128;
    int t = threadIdx.x;
    int wave = t >> 6, lane = t & 63;
    int q = lane >> 4, mn = lane & 15;
    int m0 = (bid % 63) * 16;
    int n0 = (bid / 63) * 128 + wave * 32;
    int slice = (bid / 63) * 4 + wave;
    int rr = m0 + mn;
    if (rr >= NN) rr = NN - 1;

    half8 afa[NK];
    half8 bfa[NK][2];
#pragma unroll
    for (int kk = 0; kk < NK; kk++) {
        int ka = kk * 32 + q * 8;
        const float* p = X + (size_t)rr * Kd + ka;
        floatx4 x0 = *(const floatx4*)p;
        floatx4 x1 = *(const floatx4*)(p + 4);
        half8 aa;
#pragma unroll
        for (int j = 0; j < 4; j++) { aa[j] = (_Float16)x0[j]; aa[4 + j] = (_Float16)x1[j]; }
        afa[kk] = aa;
#pragma unroll
        for (int nt = 0; nt < 2; nt++) {
            int n = slice * 32 + nt * 16 + mn;
            int k = kk * 32 + q * 8;
            half8 bb;
            if (n < 256) {
                const float* pa = w0 + (size_t)n * 256 + k;
                floatx4 a0 = *(const floatx4*)pa;
                floatx4 a1 = *(const floatx4*)(pa + 4);
                floatx4 c0 = *(const floatx4*)(pa + 128);
                floatx4 c1 = *(const floatx4*)(pa + 132);
#pragma unroll
                for (int j = 0; j < 4; j++) {
                    bb[j] = (_Float16)(a0[j] - c0[j]);
                    bb[4 + j] = (_Float16)(a1[j] - c1[j]);
                }
            } else {
                const float* pb = w0 + (size_t)(n - 256) * 256 + 128 + k;
                floatx4 c0 = *(const floatx4*)pb;
                floatx4 c1 = *(const floatx4*)(pb + 4);
#pragma unroll
                for (int j = 0; j < 4; j++) {
                    bb[j] = (_Float16)c0[j];
                    bb[4 + j] = (_Float16)c1[j];
                }
            }
            bfa[kk][nt] = bb;
        }
    }
    floatx4 acc[2] = {};
#pragma unroll
    for (int kk = 0; kk < NK; kk++) {
        acc[0] = __builtin_amdgcn_mfma_f32_16x16x32_f16(afa[kk], bfa[kk][0], acc[0], 0, 0, 0);
        acc[1] = __builtin_amdgcn_mfma_f32_16x16x32_f16(afa[kk], bfa[kk][1], acc[1], 0, 0, 0);
    }
#pragma unroll
    for (int nt = 0; nt < 2; nt++) {
        int col = n0 + nt * 16 + mn;
        float bias = (col < 256) ? b0[col] : 0.f;
#pragma unroll
        for (int r2 = 0; r2 < 4; r2++) {
            int orow = m0 + q * 4 + r2;
            if (orow < NN)
                out[(size_t)orow * 512 + col] = (_Float16)(acc[nt][r2] + bias);
        }
    }
}

// ONE pre dispatch: hist (16 private regions) || layer-0 node GEMM || chores.
__global__ __launch_bounds__(256) void k_pre1(PrepArgs pa,
                                              const int* __restrict__ ei,
                                              const float* __restrict__ X,
                                              const float* __restrict__ b0_0,
                                              _Float16* __restrict__ node_ab,
                                              _Float16* wnode, _Float16* w2h,
                                              int* cnts16, int* cursor,
                                              float* agg0, float* dout) {
    int bid = blockIdx.x;
    int t = threadIdx.x;
    if (bid < 16) {
        // private region: zero (block-local), sync, histogram own edge share
        int* my = cnts16 + bid * 1024;
        for (int i = t; i < 1024; i += 256) my[i] = 0;
        __syncthreads();
        for (int e = bid * 256 + t; e < NE; e += 16 * 256)
            atomicAdd(&my[ei[NE + e] & 1023], 1);
    } else if (bid < 16 + 252) {
        node_tile0(X, pa.w0[0], b0_0, node_ab, bid - 16);
    } else {
        // chores, grid-strided over 256 virtual blocks
        int gtid = (bid - 268) * 256 + t;
        int gs = 256 * 256;
        for (int i = gtid; i < 1024; i += gs) cursor[i] = 0;
        // wnode layers 1..4 -> fragment order (KK=8, D=256)
        for (int l = 1; l < 5; l++) {
            const float* w0 = pa.w0[l];
            _Float16* wn = wnode + l * 131072;
            for (int i = gtid; i < 131072; i += gs) {
                int j = i & 7;
                int lane = (i >> 3) & 63;
                int nt = (i >> 9) & 1;
                int kk = (i >> 10) & 7;
                int slice = i >> 13;
                int mn = lane & 15, q = lane >> 4;
                int n = slice * 32 + nt * 16 + mn;
                int k = kk * 32 + q * 8 + j;
                float v = (n < 256) ? (w0[n * 512 + k] - w0[n * 512 + 256 + k])
                                    : w0[(n - 256) * 512 + 256 + k];
                wn[i] = (_Float16)v;
            }
        }
        // W2 all 5 layers -> fragment order
        for (int l = 0; l < 5; l++) {
            const float* w1 = pa.w1[l];
            _Float16* w2 = w2h + l * 65536;
            for (int i = gtid; i < 65536; i += gs) {
                int j = i & 7;
                int lane = (i >> 3) & 63;
                int nt = (i >> 9) & 3;
                int kk = (i >> 11) & 7;
                int ws = (i >> 14) & 3;
                int mn = lane & 15, q = lane >> 4;
                int row = ws * 64 + nt * 16 + mn;
                int col = kk * 32 + q * 8 + j;
                w2[i] = (_Float16)w1[row * 256 + col];
            }
        }
        // zero agg0..agg3 (contiguous) and d_out
        floatx4 z = {0.f, 0.f, 0.f, 0.f};
        floatx4* p4 = (floatx4*)agg0;
        for (int i = gtid; i < 4 * NN * HH / 4; i += gs) p4[i] = z;
        floatx4* o4 = (floatx4*)dout;
        for (int i = gtid; i < NN * HH / 4; i += gs) o4[i] = z;
    }
}

// Per-block replicated exclusive scan (sums the 16 private hist regions),
// then counting-sort scatter of (src,dst) by dst.
__global__ __launch_bounds__(256) void k_scatter2(const int* __restrict__ ei,
                                                  const int* __restrict__ cnts16,
                                                  int* __restrict__ cursor,
                                                  int* __restrict__ ssrc,
                                                  int* __restrict__ sdst) {
    __shared__ int sbase[1024];
    __shared__ int ssum[256];
    int t = threadIdx.x;
    int base = t * 4;
    int c4[4]; int sum = 0;
#pragma unroll
    for (int j = 0; j < 4; j++) {
        int c = 0;
#pragma unroll
        for (int b = 0; b < 16; b++) c += cnts16[b * 1024 + base + j];
        c4[j] = c; sum += c;
    }
    ssum[t] = sum;
    __syncthreads();
    for (int d = 1; d < 256; d <<= 1) {
        int v = (t >= d) ? ssum[t - d] : 0;
        __syncthreads();
        ssum[t] += v;
        __syncthreads();
    }
    int run = (t > 0) ? ssum[t - 1] : 0;
#pragma unroll
    for (int j = 0; j < 4; j++) { sbase[base + j] = run; run += c4[j]; }
    __syncthreads();
    for (int e = blockIdx.x * 256 + t; e < NE; e += gridDim.x * 256) {
        int s = ei[e] & 1023, d = ei[NE + e] & 1023;
        int pos = sbase[d] + atomicAdd(&cursor[d], 1);
        if (pos < NE) { ssrc[pos] = s; sdst[pos] = d; }
    }
}

// pure node GEMM layer l+1 (reads agg_in), 252 blocks
__global__ __launch_bounds__(256) void k_node(const float* __restrict__ agg_in,
                                              const _Float16* __restrict__ Wn,
                                              const float* __restrict__ b0,
                                              _Float16* __restrict__ out) {
    node_tile<8>(agg_in, Wn, b0, out, blockIdx.x);
}

// 64 sorted edges x 256 cols: stage h1 = relu(a[dst]+b[src]) XOR-swizzled in
// LDS, MFMA vs fragment-ordered W2 -> acc[4][4]. (Verified r0/r3 body.)
__device__ __forceinline__ void edge_mfma(const _Float16* __restrict__ node_ab,
                                          const int* __restrict__ ssrc,
                                          const int* __restrict__ sdst,
                                          const _Float16* __restrict__ W2,
                                          int tile, _Float16* h1, int* sd,
                                          floatx4 acc[4][4]) {
    int t = threadIdx.x;
    int e0 = tile * 64;
    int wave = t >> 6, lane = t & 63;
    int q = lane >> 4, mn = lane & 15;
    const _Float16* W2w = W2 + wave * 16384;

    if (t < 64) sd[t] = sdst[e0 + t];
    {
        int row = t & 63;
        int cb = (t >> 6) * 8;
        int dn = sdst[e0 + row], sn = ssrc[e0 + row];
        const _Float16* pa = node_ab + (size_t)dn * 512 + cb * 8;
        const _Float16* pb = node_ab + (size_t)sn * 512 + 256 + cb * 8;
        half8 av[8], bv[8];
#pragma unroll
        for (int i = 0; i < 8; i++) av[i] = *(const half8*)(pa + i * 8);
#pragma unroll
        for (int i = 0; i < 8; i++) bv[i] = *(const half8*)(pb + i * 8);
#pragma unroll
        for (int i = 0; i < 8; i++) {
            int c = cb + i;
            int p = (c & ~7) | ((c ^ row) & 7);
            half8 hv = av[i] + bv[i];
#pragma unroll
            for (int j = 0; j < 8; j++) hv[j] = hv[j] > (_Float16)0 ? hv[j] : (_Float16)0;
            *(half8*)(&h1[row * 256 + p * 8]) = hv;
        }
    }
    __syncthreads();

#pragma unroll
    for (int kk = 0; kk < 8; kk++) {
        half8 bf[4];
#pragma unroll
        for (int nt = 0; nt < 4; nt++)
            bf[nt] = *(const half8*)(W2w + (kk * 4 + nt) * 512 + lane * 8);  // coalesced
        half8 af[4];
#pragma unroll
        for (int mt = 0; mt < 4; mt++) {
            int r = mt * 16 + mn;
            int c = kk * 4 + q;
            int p = (c & ~7) | ((c ^ r) & 7);
            af[mt] = *(const half8*)(&h1[r * 256 + p * 8]);
        }
#pragma unroll
        for (int mt = 0; mt < 4; mt++)
#pragma unroll
            for (int nt = 0; nt < 4; nt++)
                acc[mt][nt] = __builtin_amdgcn_mfma_f32_16x16x32_f16(af[mt], bf[nt], acc[mt][nt], 0, 0, 0);
    }
}

// middle layers: h2=relu(acc+bias) -> fp16 LDS (same swizzle), column-owner
// run scan; interior runs plain-store, boundary runs atomicMax. agg pre-zeroed.
__global__ __launch_bounds__(256, 4) void edge_gemm2(const _Float16* __restrict__ node_ab,
                          const int* __restrict__ ssrc, const int* __restrict__ sdst,
                          const _Float16* __restrict__ W2, const float* __restrict__ b2,
                          float* __restrict__ agg) {
    __shared__ _Float16 h1[64 * 256];
    __shared__ int sd[64];
    int t = threadIdx.x;
    int wave = t >> 6, lane = t & 63;
    int q = lane >> 4, mn = lane & 15;

    floatx4 acc[4][4] = {};
    edge_mfma(node_ab, ssrc, sdst, W2, blockIdx.x, h1, sd, acc);

    __syncthreads();  // all h1 fragment reads done before overwrite
#pragma unroll
    for (int nt = 0; nt < 4; nt++) {
        int col = wave * 64 + nt * 16 + mn;
        float bias = b2[col];
        int g = col >> 3, o = col & 7;
#pragma unroll
        for (int mt = 0; mt < 4; mt++) {
#pragma unroll
            for (int r2 = 0; r2 < 4; r2++) {
                int row = mt * 16 + q * 4 + r2;
                float v = acc[mt][nt][r2] + bias;
                v = v > 0.f ? v : 0.f;
                int pg = (g & ~7) | ((g ^ row) & 7);
                h1[row * 256 + pg * 8 + o] = (_Float16)v;
            }
        }
    }
    __syncthreads();

    {
        int c = t;
        int g = c >> 3, o = c & 7;
        float* aggc = agg + c;
        float m = (float)h1[g * 8 + o];  // row 0: pg = g
        bool sedge = true;
        int prevd = sd[0];
#pragma unroll 8
        for (int r = 1; r < 64; r++) {
            int d = sd[r];
            int pg = (g & ~7) | ((g ^ r) & 7);
            float v = (float)h1[r * 256 + pg * 8 + o];
            if (d != prevd) {
                if (sedge) {
                    if (m > 0.f)
                        atomicMax((unsigned int*)(aggc + (size_t)prevd * HH), __float_as_uint(m));
                } else {
                    if (m > 0.f)
                        aggc[(size_t)prevd * HH] = m;   // block-exclusive
                }
                m = v; sedge = false; prevd = d;
            } else {
                m = fmaxf(m, v);
            }
        }
        if (m > 0.f)
            atomicMax((unsigned int*)(aggc + (size_t)prevd * HH), __float_as_uint(m));
    }
}

// last layer: exact-fp32 two-pass epilogue (padded-stride LDS transpose;
// interior runs plain-store; d_out numerics identical to atomic baseline).
__global__ __launch_bounds__(256, 4) void edge_last(
        const _Float16* __restrict__ node_ab,
        const int* __restrict__ ssrc, const int* __restrict__ sdst,
        const _Float16* __restrict__ W2, const float* __restrict__ b2,
        float* __restrict__ agg) {
    __shared__ float sf[64 * 129];   // 33 KB; stride 129 -> conflict-free scan
    __shared__ int sd[64];
    _Float16* h1 = (_Float16*)sf;    // 32 KB alias for the staging/MFMA phase
    int t = threadIdx.x;
    int wave = t >> 6, lane = t & 63;
    int q = lane >> 4, mn = lane & 15;

    floatx4 acc[4][4] = {};
    edge_mfma(node_ab, ssrc, sdst, W2, blockIdx.x, h1, sd, acc);

    __syncthreads();  // h1 reads done
#pragma unroll
    for (int p = 0; p < 2; p++) {
        if (p) __syncthreads();      // pass-0 scan done before rewrite
        if ((wave >> 1) == p) {
            int lc0 = (wave & 1) * 64;
#pragma unroll
            for (int nt = 0; nt < 4; nt++) {
                int col = wave * 64 + nt * 16 + mn;
                float bias = b2[col];
                int lc = lc0 + nt * 16 + mn;
#pragma unroll
                for (int mt = 0; mt < 4; mt++) {
#pragma unroll
                    for (int r2 = 0; r2 < 4; r2++) {
                        int row = mt * 16 + q * 4 + r2;
                        float v = acc[mt][nt][r2] + bias;
                        sf[row * 129 + lc] = v > 0.f ? v : 0.f;
                    }
                }
            }
        }
        __syncthreads();
        if (t < 128) {
            float* aggc = agg + p * 128 + t;
            float m = sf[t];
            bool sedge = true;
            int prevd = sd[0];
#pragma unroll 8
            for (int r = 1; r < 64; r++) {
                int d = sd[r];
                float v = sf[r * 129 + t];
                if (d != prevd) {
                    if (sedge) {
                        if (m > 0.f)
                            atomicMax((unsigned int*)(aggc + (size_t)prevd * HH), __float_as_uint(m));
                    } else {
                        if (m > 0.f)
                            aggc[(size_t)prevd * HH] = m;
                    }
                    m = v; sedge = false; prevd = d;
                } else {
                    m = fmaxf(m, v);
                }
            }
            if (m > 0.f)
                atomicMax((unsigned int*)(aggc + (size_t)prevd * HH), __float_as_uint(m));
        }
    }
}

extern "C" void kernel_launch(void* const* d_in, const int* in_sizes, int n_in,
                              void* d_out, int out_size, void* d_ws, size_t ws_size,
                              hipStream_t stream) {
    const float* x = (const float*)d_in[0];
    const int* ei = (const int*)d_in[1];  // int32 per harness contract
    PrepArgs pa;
    const float* b0s[5];
    const float* b1s[5];
    for (int l = 0; l < 5; l++) {
        pa.w0[l] = (const float*)d_in[2 + 4 * l];
        b0s[l] = (const float*)d_in[3 + 4 * l];
        pa.w1[l] = (const float*)d_in[4 + 4 * l];
        b1s[l] = (const float*)d_in[5 + 4 * l];
    }

    int* ssrc = (int*)d_ws;                              // 256 KB
    int* sdst = ssrc + NE;                               // 256 KB
    int* cnts16 = sdst + NE;                             // 16 x 1024 ints, 64 KB
    int* cursor = cnts16 + 16 * 1024;                    // 4 KB
    _Float16* node_ab = (_Float16*)(cursor + 1024);      // [1024][512] fp16, 1 MB
    float* agg0 = (float*)(node_ab + 1024 * 512);        // 4 x 1 MB (contiguous)
    float* agg1 = agg0 + NN * HH;
    float* agg2 = agg1 + NN * HH;
    float* agg3 = agg2 + NN * HH;
    _Float16* wnode = (_Float16*)(agg3 + NN * HH);       // 5 x 131072 halfs (slot 0 unused)
    _Float16* w2h = wnode + 5 * 131072;                  // 5 x 65536 halfs

    hipLaunchKernelGGL(k_pre1, dim3(524), dim3(256), 0, stream,
                       pa, ei, x, b0s[0], node_ab, wnode, w2h,
                       cnts16, cursor, agg0, (float*)d_out);
    hipLaunchKernelGGL(k_scatter2, dim3(NE / 256), dim3(256), 0, stream,
                       ei, cnts16, cursor, ssrc, sdst);

    float* aggs[4] = {agg0, agg1, agg2, agg3};
    for (int l = 0; l < 4; l++) {
        hipLaunchKernelGGL(edge_gemm2, dim3(NE / 64), dim3(256), 0, stream,
                           node_ab, ssrc, sdst, w2h + (size_t)l * 65536, b1s[l], aggs[l]);
        hipLaunchKernelGGL(k_node, dim3(252), dim3(256), 0, stream,
                           aggs[l], wnode + (size_t)(l + 1) * 131072, b0s[l + 1], node_ab);
    }
    hipLaunchKernelGGL(edge_last, dim3(NE / 64), dim3(256), 0, stream,
                       node_ab, ssrc, sdst, w2h + (size_t)4 * 65536, b1s[4],
                       (float*)d_out);
}

// Round 9
// 237.505 us; speedup vs baseline: 3.0314x; 1.0650x over previous
//
#include <hip/hip_runtime.h>

#define NN 1000
#define NE 64000
#define HH 256

typedef _Float16 half8 __attribute__((ext_vector_type(8)));
typedef float floatx4 __attribute__((ext_vector_type(4)));

struct PrepArgs { const float* w0[5]; const float* w1[5]; };

// ---------------------------------------------------------------------------
// Pipeline (11 dispatches; boundary ~2 µs. In-kernel cross-block sync BANNED:
// grid.sync ~110 µs (r1), threadfence flag-barrier ~115 µs (r4)).
//   1. k_pre1    : hist (16 private regions) || layer-0 node GEMM (in-kernel
//                  weight conversion) || chores (swizzles + zeroing)
//   2. k_scatter2: replicated scan (sums 16 regions) + counting-sort scatter
//   3..10. 4 x (edge_gemm2 + k_node), 11. edge_last
// edge staging (r9): COALESCED gather — 32 lanes read 32 consecutive 16-B
// slots of ONE half-row (16 cache lines/wave-instr vs 64 with the old
// row-per-lane layout -> 4x less L1 line servicing). Indices broadcast from
// LDS. Same values, same XOR swizzle -> bit-identical h1.
// edge epilogue: interior sorted runs block-exclusive -> plain store; only
// runs touching tile row 0/63 use device atomicMax. Last layer: exact-fp32
// two-pass epilogue (d_out numerics identical to baseline).
// ---------------------------------------------------------------------------

// C = X[M,Kd] @ Wn^T, 16x128 tile per block (252 tiles); Wn in fragment order.
template <int NK>
__device__ __forceinline__ void node_tile(const float* __restrict__ X,
                                          const _Float16* __restrict__ Wn,
                                          const float* __restrict__ b0,
                                          _Float16* __restrict__ out, int bid) {
    const int Kd = NK * 32;
    int t = threadIdx.x;
    int wave = t >> 6, lane = t & 63;
    int q = lane >> 4, mn = lane & 15;
    int m0 = (bid % 63) * 16;
    int n0 = (bid / 63) * 128 + wave * 32;
    int slice = (bid / 63) * 4 + wave;
    int rr = m0 + mn;
    if (rr >= NN) rr = NN - 1;

    half8 afa[NK];
    half8 bfa[NK][2];
#pragma unroll
    for (int kk = 0; kk < NK; kk++) {
        int ka = kk * 32 + q * 8;
        const float* p = X + (size_t)rr * Kd + ka;
        floatx4 x0 = *(const floatx4*)p;
        floatx4 x1 = *(const floatx4*)(p + 4);
        half8 aa;
#pragma unroll
        for (int j = 0; j < 4; j++) { aa[j] = (_Float16)x0[j]; aa[4 + j] = (_Float16)x1[j]; }
        afa[kk] = aa;
        bfa[kk][0] = *(const half8*)(Wn + (((slice * NK + kk) * 2 + 0) * 64 + lane) * 8);
        bfa[kk][1] = *(const half8*)(Wn + (((slice * NK + kk) * 2 + 1) * 64 + lane) * 8);
    }
    floatx4 acc[2] = {};
#pragma unroll
    for (int kk = 0; kk < NK; kk++) {
        acc[0] = __builtin_amdgcn_mfma_f32_16x16x32_f16(afa[kk], bfa[kk][0], acc[0], 0, 0, 0);
        acc[1] = __builtin_amdgcn_mfma_f32_16x16x32_f16(afa[kk], bfa[kk][1], acc[1], 0, 0, 0);
    }
#pragma unroll
    for (int nt = 0; nt < 2; nt++) {
        int col = n0 + nt * 16 + mn;
        float bias = (col < 256) ? b0[col] : 0.f;
#pragma unroll
        for (int r2 = 0; r2 < 4; r2++) {
            int orow = m0 + q * 4 + r2;
            if (orow < NN)
                out[(size_t)orow * 512 + col] = (_Float16)(acc[nt][r2] + bias);
        }
    }
}

// layer-0 node GEMM with IN-KERNEL fp32->fp16 fragment conversion from w0.
__device__ __forceinline__ void node_tile0(const float* __restrict__ X,
                                           const float* __restrict__ w0,
                                           const float* __restrict__ b0,
                                           _Float16* __restrict__ out, int bid) {
    const int NK = 4;
    const int Kd = 128;
    int t = threadIdx.x;
    int wave = t >> 6, lane = t & 63;
    int q = lane >> 4, mn = lane & 15;
    int m0 = (bid % 63) * 16;
    int n0 = (bid / 63) * 128 + wave * 32;
    int slice = (bid / 63) * 4 + wave;
    int rr = m0 + mn;
    if (rr >= NN) rr = NN - 1;

    half8 afa[NK];
    half8 bfa[NK][2];
#pragma unroll
    for (int kk = 0; kk < NK; kk++) {
        int ka = kk * 32 + q * 8;
        const float* p = X + (size_t)rr * Kd + ka;
        floatx4 x0 = *(const floatx4*)p;
        floatx4 x1 = *(const floatx4*)(p + 4);
        half8 aa;
#pragma unroll
        for (int j = 0; j < 4; j++) { aa[j] = (_Float16)x0[j]; aa[4 + j] = (_Float16)x1[j]; }
        afa[kk] = aa;
#pragma unroll
        for (int nt = 0; nt < 2; nt++) {
            int n = slice * 32 + nt * 16 + mn;
            int k = kk * 32 + q * 8;
            half8 bb;
            if (n < 256) {
                const float* pa = w0 + (size_t)n * 256 + k;
                floatx4 a0 = *(const floatx4*)pa;
                floatx4 a1 = *(const floatx4*)(pa + 4);
                floatx4 c0 = *(const floatx4*)(pa + 128);
                floatx4 c1 = *(const floatx4*)(pa + 132);
#pragma unroll
                for (int j = 0; j < 4; j++) {
                    bb[j] = (_Float16)(a0[j] - c0[j]);
                    bb[4 + j] = (_Float16)(a1[j] - c1[j]);
                }
            } else {
                const float* pb = w0 + (size_t)(n - 256) * 256 + 128 + k;
                floatx4 c0 = *(const floatx4*)pb;
                floatx4 c1 = *(const floatx4*)(pb + 4);
#pragma unroll
                for (int j = 0; j < 4; j++) {
                    bb[j] = (_Float16)c0[j];
                    bb[4 + j] = (_Float16)c1[j];
                }
            }
            bfa[kk][nt] = bb;
        }
    }
    floatx4 acc[2] = {};
#pragma unroll
    for (int kk = 0; kk < NK; kk++) {
        acc[0] = __builtin_amdgcn_mfma_f32_16x16x32_f16(afa[kk], bfa[kk][0], acc[0], 0, 0, 0);
        acc[1] = __builtin_amdgcn_mfma_f32_16x16x32_f16(afa[kk], bfa[kk][1], acc[1], 0, 0, 0);
    }
#pragma unroll
    for (int nt = 0; nt < 2; nt++) {
        int col = n0 + nt * 16 + mn;
        float bias = (col < 256) ? b0[col] : 0.f;
#pragma unroll
        for (int r2 = 0; r2 < 4; r2++) {
            int orow = m0 + q * 4 + r2;
            if (orow < NN)
                out[(size_t)orow * 512 + col] = (_Float16)(acc[nt][r2] + bias);
        }
    }
}

// ONE pre dispatch: hist (16 private regions) || layer-0 node GEMM || chores.
__global__ __launch_bounds__(256) void k_pre1(PrepArgs pa,
                                              const int* __restrict__ ei,
                                              const float* __restrict__ X,
                                              const float* __restrict__ b0_0,
                                              _Float16* __restrict__ node_ab,
                                              _Float16* wnode, _Float16* w2h,
                                              int* cnts16, int* cursor,
                                              float* agg0, float* dout) {
    int bid = blockIdx.x;
    int t = threadIdx.x;
    if (bid < 16) {
        int* my = cnts16 + bid * 1024;
        for (int i = t; i < 1024; i += 256) my[i] = 0;
        __syncthreads();
        for (int e = bid * 256 + t; e < NE; e += 16 * 256)
            atomicAdd(&my[ei[NE + e] & 1023], 1);
    } else if (bid < 16 + 252) {
        node_tile0(X, pa.w0[0], b0_0, node_ab, bid - 16);
    } else {
        int gtid = (bid - 268) * 256 + t;
        int gs = 256 * 256;
        for (int i = gtid; i < 1024; i += gs) cursor[i] = 0;
        for (int l = 1; l < 5; l++) {
            const float* w0 = pa.w0[l];
            _Float16* wn = wnode + l * 131072;
            for (int i = gtid; i < 131072; i += gs) {
                int j = i & 7;
                int lane = (i >> 3) & 63;
                int nt = (i >> 9) & 1;
                int kk = (i >> 10) & 7;
                int slice = i >> 13;
                int mn = lane & 15, q = lane >> 4;
                int n = slice * 32 + nt * 16 + mn;
                int k = kk * 32 + q * 8 + j;
                float v = (n < 256) ? (w0[n * 512 + k] - w0[n * 512 + 256 + k])
                                    : w0[(n - 256) * 512 + 256 + k];
                wn[i] = (_Float16)v;
            }
        }
        for (int l = 0; l < 5; l++) {
            const float* w1 = pa.w1[l];
            _Float16* w2 = w2h + l * 65536;
            for (int i = gtid; i < 65536; i += gs) {
                int j = i & 7;
                int lane = (i >> 3) & 63;
                int nt = (i >> 9) & 3;
                int kk = (i >> 11) & 7;
                int ws = (i >> 14) & 3;
                int mn = lane & 15, q = lane >> 4;
                int row = ws * 64 + nt * 16 + mn;
                int col = kk * 32 + q * 8 + j;
                w2[i] = (_Float16)w1[row * 256 + col];
            }
        }
        floatx4 z = {0.f, 0.f, 0.f, 0.f};
        floatx4* p4 = (floatx4*)agg0;
        for (int i = gtid; i < 4 * NN * HH / 4; i += gs) p4[i] = z;
        floatx4* o4 = (floatx4*)dout;
        for (int i = gtid; i < NN * HH / 4; i += gs) o4[i] = z;
    }
}

// Per-block replicated exclusive scan (sums the 16 private hist regions),
// then counting-sort scatter of (src,dst) by dst.
__global__ __launch_bounds__(256) void k_scatter2(const int* __restrict__ ei,
                                                  const int* __restrict__ cnts16,
                                                  int* __restrict__ cursor,
                                                  int* __restrict__ ssrc,
                                                  int* __restrict__ sdst) {
    __shared__ int sbase[1024];
    __shared__ int ssum[256];
    int t = threadIdx.x;
    int base = t * 4;
    int c4[4]; int sum = 0;
#pragma unroll
    for (int j = 0; j < 4; j++) {
        int c = 0;
#pragma unroll
        for (int b = 0; b < 16; b++) c += cnts16[b * 1024 + base + j];
        c4[j] = c; sum += c;
    }
    ssum[t] = sum;
    __syncthreads();
    for (int d = 1; d < 256; d <<= 1) {
        int v = (t >= d) ? ssum[t - d] : 0;
        __syncthreads();
        ssum[t] += v;
        __syncthreads();
    }
    int run = (t > 0) ? ssum[t - 1] : 0;
#pragma unroll
    for (int j = 0; j < 4; j++) { sbase[base + j] = run; run += c4[j]; }
    __syncthreads();
    for (int e = blockIdx.x * 256 + t; e < NE; e += gridDim.x * 256) {
        int s = ei[e] & 1023, d = ei[NE + e] & 1023;
        int pos = sbase[d] + atomicAdd(&cursor[d], 1);
        if (pos < NE) { ssrc[pos] = s; sdst[pos] = d; }
    }
}

// pure node GEMM layer l+1 (reads agg_in), 252 blocks
__global__ __launch_bounds__(256) void k_node(const float* __restrict__ agg_in,
                                              const _Float16* __restrict__ Wn,
                                              const float* __restrict__ b0,
                                              _Float16* __restrict__ out) {
    node_tile<8>(agg_in, Wn, b0, out, blockIdx.x);
}

// 64 sorted edges x 256 cols. COALESCED staging (r9): indices -> LDS
// (sd[0..63]=dst, sd[64..127]=src), then per iteration each wave's 2x32
// lanes read 2 half-rows as contiguous 512-B segments (16 lines/instr).
// h1 = relu(a[dst]+b[src]) XOR-swizzled (same formula, c = slot s) -> MFMA
// vs fragment-ordered W2 -> acc[4][4]. Bit-identical to the old staging.
__device__ __forceinline__ void edge_mfma(const _Float16* __restrict__ node_ab,
                                          const int* __restrict__ ssrc,
                                          const int* __restrict__ sdst,
                                          const _Float16* __restrict__ W2,
                                          int tile, _Float16* h1, int* sd,
                                          floatx4 acc[4][4]) {
    int t = threadIdx.x;
    int e0 = tile * 64;
    int wave = t >> 6, lane = t & 63;
    int q = lane >> 4, mn = lane & 15;
    const _Float16* W2w = W2 + wave * 16384;

    if (t < 128) sd[t] = (t < 64) ? sdst[e0 + t] : ssrc[e0 + t - 64];
    __syncthreads();
    {
        int s = lane & 31;       // 16-B slot (8 halfs) within the 256-half half-row
        int rh = lane >> 5;      // which of the wave's two rows this iteration
#pragma unroll
        for (int it = 0; it < 8; it++) {
            int row = it * 8 + wave * 2 + rh;          // bijective over 0..63
            int dn = sd[row], sn = sd[64 + row];       // LDS broadcast
            half8 av = *(const half8*)(node_ab + (size_t)dn * 512 + s * 8);
            half8 bv = *(const half8*)(node_ab + (size_t)sn * 512 + 256 + s * 8);
            half8 hv = av + bv;
#pragma unroll
            for (int j = 0; j < 8; j++) hv[j] = hv[j] > (_Float16)0 ? hv[j] : (_Float16)0;
            int p = (s & ~7) | ((s ^ row) & 7);        // same XOR swizzle, c = s
            *(half8*)(&h1[row * 256 + p * 8]) = hv;
        }
    }
    __syncthreads();

#pragma unroll
    for (int kk = 0; kk < 8; kk++) {
        half8 bf[4];
#pragma unroll
        for (int nt = 0; nt < 4; nt++)
            bf[nt] = *(const half8*)(W2w + (kk * 4 + nt) * 512 + lane * 8);  // coalesced
        half8 af[4];
#pragma unroll
        for (int mt = 0; mt < 4; mt++) {
            int r = mt * 16 + mn;
            int c = kk * 4 + q;
            int p = (c & ~7) | ((c ^ r) & 7);
            af[mt] = *(const half8*)(&h1[r * 256 + p * 8]);
        }
#pragma unroll
        for (int mt = 0; mt < 4; mt++)
#pragma unroll
            for (int nt = 0; nt < 4; nt++)
                acc[mt][nt] = __builtin_amdgcn_mfma_f32_16x16x32_f16(af[mt], bf[nt], acc[mt][nt], 0, 0, 0);
    }
}

// middle layers: h2=relu(acc+bias) -> fp16 LDS (same swizzle), column-owner
// run scan; interior runs plain-store, boundary runs atomicMax. agg pre-zeroed.
__global__ __launch_bounds__(256, 4) void edge_gemm2(const _Float16* __restrict__ node_ab,
                          const int* __restrict__ ssrc, const int* __restrict__ sdst,
                          const _Float16* __restrict__ W2, const float* __restrict__ b2,
                          float* __restrict__ agg) {
    __shared__ _Float16 h1[64 * 256];
    __shared__ int sd[128];
    int t = threadIdx.x;
    int wave = t >> 6, lane = t & 63;
    int q = lane >> 4, mn = lane & 15;

    floatx4 acc[4][4] = {};
    edge_mfma(node_ab, ssrc, sdst, W2, blockIdx.x, h1, sd, acc);

    __syncthreads();  // all h1 fragment reads done before overwrite
#pragma unroll
    for (int nt = 0; nt < 4; nt++) {
        int col = wave * 64 + nt * 16 + mn;
        float bias = b2[col];
        int g = col >> 3, o = col & 7;
#pragma unroll
        for (int mt = 0; mt < 4; mt++) {
#pragma unroll
            for (int r2 = 0; r2 < 4; r2++) {
                int row = mt * 16 + q * 4 + r2;
                float v = acc[mt][nt][r2] + bias;
                v = v > 0.f ? v : 0.f;
                int pg = (g & ~7) | ((g ^ row) & 7);
                h1[row * 256 + pg * 8 + o] = (_Float16)v;
            }
        }
    }
    __syncthreads();

    {
        int c = t;
        int g = c >> 3, o = c & 7;
        float* aggc = agg + c;
        float m = (float)h1[g * 8 + o];  // row 0: pg = g
        bool sedge = true;
        int prevd = sd[0];
#pragma unroll 8
        for (int r = 1; r < 64; r++) {
            int d = sd[r];
            int pg = (g & ~7) | ((g ^ r) & 7);
            float v = (float)h1[r * 256 + pg * 8 + o];
            if (d != prevd) {
                if (sedge) {
                    if (m > 0.f)
                        atomicMax((unsigned int*)(aggc + (size_t)prevd * HH), __float_as_uint(m));
                } else {
                    if (m > 0.f)
                        aggc[(size_t)prevd * HH] = m;   // block-exclusive
                }
                m = v; sedge = false; prevd = d;
            } else {
                m = fmaxf(m, v);
            }
        }
        if (m > 0.f)
            atomicMax((unsigned int*)(aggc + (size_t)prevd * HH), __float_as_uint(m));
    }
}

// last layer: exact-fp32 two-pass epilogue (padded-stride LDS transpose;
// interior runs plain-store; d_out numerics identical to atomic baseline).
__global__ __launch_bounds__(256, 4) void edge_last(
        const _Float16* __restrict__ node_ab,
        const int* __restrict__ ssrc, const int* __restrict__ sdst,
        const _Float16* __restrict__ W2, const float* __restrict__ b2,
        float* __restrict__ agg) {
    __shared__ float sf[64 * 129];   // 33 KB; stride 129 -> conflict-free scan
    __shared__ int sd[128];
    _Float16* h1 = (_Float16*)sf;    // 32 KB alias for the staging/MFMA phase
    int t = threadIdx.x;
    int wave = t >> 6, lane = t & 63;
    int q = lane >> 4, mn = lane & 15;

    floatx4 acc[4][4] = {};
    edge_mfma(node_ab, ssrc, sdst, W2, blockIdx.x, h1, sd, acc);

    __syncthreads();  // h1 reads done
#pragma unroll
    for (int p = 0; p < 2; p++) {
        if (p) __syncthreads();      // pass-0 scan done before rewrite
        if ((wave >> 1) == p) {
            int lc0 = (wave & 1) * 64;
#pragma unroll
            for (int nt = 0; nt < 4; nt++) {
                int col = wave * 64 + nt * 16 + mn;
                float bias = b2[col];
                int lc = lc0 + nt * 16 + mn;
#pragma unroll
                for (int mt = 0; mt < 4; mt++) {
#pragma unroll
                    for (int r2 = 0; r2 < 4; r2++) {
                        int row = mt * 16 + q * 4 + r2;
                        float v = acc[mt][nt][r2] + bias;
                        sf[row * 129 + lc] = v > 0.f ? v : 0.f;
                    }
                }
            }
        }
        __syncthreads();
        if (t < 128) {
            float* aggc = agg + p * 128 + t;
            float m = sf[t];
            bool sedge = true;
            int prevd = sd[0];
#pragma unroll 8
            for (int r = 1; r < 64; r++) {
                int d = sd[r];
                float v = sf[r * 129 + t];
                if (d != prevd) {
                    if (sedge) {
                        if (m > 0.f)
                            atomicMax((unsigned int*)(aggc + (size_t)prevd * HH), __float_as_uint(m));
                    } else {
                        if (m > 0.f)
                            aggc[(size_t)prevd * HH] = m;
                    }
                    m = v; sedge = false; prevd = d;
                } else {
                    m = fmaxf(m, v);
                }
            }
            if (m > 0.f)
                atomicMax((unsigned int*)(aggc + (size_t)prevd * HH), __float_as_uint(m));
        }
    }
}

extern "C" void kernel_launch(void* const* d_in, const int* in_sizes, int n_in,
                              void* d_out, int out_size, void* d_ws, size_t ws_size,
                              hipStream_t stream) {
    const float* x = (const float*)d_in[0];
    const int* ei = (const int*)d_in[1];  // int32 per harness contract
    PrepArgs pa;
    const float* b0s[5];
    const float* b1s[5];
    for (int l = 0; l < 5; l++) {
        pa.w0[l] = (const float*)d_in[2 + 4 * l];
        b0s[l] = (const float*)d_in[3 + 4 * l];
        pa.w1[l] = (const float*)d_in[4 + 4 * l];
        b1s[l] = (const float*)d_in[5 + 4 * l];
    }

    int* ssrc = (int*)d_ws;                              // 256 KB
    int* sdst = ssrc + NE;                               // 256 KB
    int* cnts16 = sdst + NE;                             // 16 x 1024 ints, 64 KB
    int* cursor = cnts16 + 16 * 1024;                    // 4 KB
    _Float16* node_ab = (_Float16*)(cursor + 1024);      // [1024][512] fp16, 1 MB
    float* agg0 = (float*)(node_ab + 1024 * 512);        // 4 x 1 MB (contiguous)
    float* agg1 = agg0 + NN * HH;
    float* agg2 = agg1 + NN * HH;
    float* agg3 = agg2 + NN * HH;
    _Float16* wnode = (_Float16*)(agg3 + NN * HH);       // 5 x 131072 halfs (slot 0 unused)
    _Float16* w2h = wnode + 5 * 131072;                  // 5 x 65536 halfs

    hipLaunchKernelGGL(k_pre1, dim3(524), dim3(256), 0, stream,
                       pa, ei, x, b0s[0], node_ab, wnode, w2h,
                       cnts16, cursor, agg0, (float*)d_out);
    hipLaunchKernelGGL(k_scatter2, dim3(NE / 256), dim3(256), 0, stream,
                       ei, cnts16, cursor, ssrc, sdst);

    float* aggs[4] = {agg0, agg1, agg2, agg3};
    for (int l = 0; l < 4; l++) {
        hipLaunchKernelGGL(edge_gemm2, dim3(NE / 64), dim3(256), 0, stream,
                           node_ab, ssrc, sdst, w2h + (size_t)l * 65536, b1s[l], aggs[l]);
        hipLaunchKernelGGL(k_node, dim3(252), dim3(256), 0, stream,
                           aggs[l], wnode + (size_t)(l + 1) * 131072, b0s[l + 1], node_ab);
    }
    hipLaunchKernelGGL(edge_last, dim3(NE / 64), dim3(256), 0, stream,
                       node_ab, ssrc, sdst, w2h + (size_t)4 * 65536, b1s[4],
                       (float*)d_out);
}

// Round 11
// 234.310 us; speedup vs baseline: 3.0727x; 1.0136x over previous
//
#include <hip/hip_runtime.h>

#define NN 1000
#define NE 64000
#define HH 256

typedef _Float16 half8 __attribute__((ext_vector_type(8)));
typedef float floatx4 __attribute__((ext_vector_type(4)));

struct PrepArgs { const float* w0[5]; const float* w1[5]; };

// ---------------------------------------------------------------------------
// Pipeline (11 dispatches; boundary ~2 µs. In-kernel cross-block sync BANNED:
// grid.sync ~110 µs (r1), threadfence flag-barrier ~115 µs (r4)).
//   1. k_pre1    : hist (16 private regions) || layer-0 node GEMM (in-kernel
//                  weight conversion) || chores (swizzles + zeroing)
//   2. k_scatter2: replicated scan + counting-sort scatter + CHUNK TABLE:
//                  one entry per (dst, <=64 edges) chunk (block 0 writes it)
//   3..11. 5 x edge_gemm3 (+ 4 x k_node interleaved)
// edge_gemm3 (r10): block = ONE dst chunk. dst uniform -> a-row loaded once
// per lane; coalesced b-gather (r9 layout); padded rows masked in-register.
// Epilogue = masked reg-max + 2 shfl_xor over q-lanes -> one coalesced store
// per thread. Sole-chunk dsts (~53%): plain store, ZERO atomics. Split dsts:
// atomicMax (2-way contention). Replaces the per-tile h2 LDS writeback +
// 64-iter serial run scan + ~1M atomics/layer of the fixed-tile scheme.
// relu(max+bias)=max(relu(acc_i+bias)) exact by monotone fp32 rounding.
// ---------------------------------------------------------------------------

// C = X[M,Kd] @ Wn^T, 16x128 tile per block (252 tiles); Wn in fragment order.
template <int NK>
__device__ __forceinline__ void node_tile(const float* __restrict__ X,
                                          const _Float16* __restrict__ Wn,
                                          const float* __restrict__ b0,
                                          _Float16* __restrict__ out, int bid) {
    const int Kd = NK * 32;
    int t = threadIdx.x;
    int wave = t >> 6, lane = t & 63;
    int q = lane >> 4, mn = lane & 15;
    int m0 = (bid % 63) * 16;
    int n0 = (bid / 63) * 128 + wave * 32;
    int slice = (bid / 63) * 4 + wave;
    int rr = m0 + mn;
    if (rr >= NN) rr = NN - 1;

    half8 afa[NK];
    half8 bfa[NK][2];
#pragma unroll
    for (int kk = 0; kk < NK; kk++) {
        int ka = kk * 32 + q * 8;
        const float* p = X + (size_t)rr * Kd + ka;
        floatx4 x0 = *(const floatx4*)p;
        floatx4 x1 = *(const floatx4*)(p + 4);
        half8 aa;
#pragma unroll
        for (int j = 0; j < 4; j++) { aa[j] = (_Float16)x0[j]; aa[4 + j] = (_Float16)x1[j]; }
        afa[kk] = aa;
        bfa[kk][0] = *(const half8*)(Wn + (((slice * NK + kk) * 2 + 0) * 64 + lane) * 8);
        bfa[kk][1] = *(const half8*)(Wn + (((slice * NK + kk) * 2 + 1) * 64 + lane) * 8);
    }
    floatx4 acc[2] = {};
#pragma unroll
    for (int kk = 0; kk < NK; kk++) {
        acc[0] = __builtin_amdgcn_mfma_f32_16x16x32_f16(afa[kk], bfa[kk][0], acc[0], 0, 0, 0);
        acc[1] = __builtin_amdgcn_mfma_f32_16x16x32_f16(afa[kk], bfa[kk][1], acc[1], 0, 0, 0);
    }
#pragma unroll
    for (int nt = 0; nt < 2; nt++) {
        int col = n0 + nt * 16 + mn;
        float bias = (col < 256) ? b0[col] : 0.f;
#pragma unroll
        for (int r2 = 0; r2 < 4; r2++) {
            int orow = m0 + q * 4 + r2;
            if (orow < NN)
                out[(size_t)orow * 512 + col] = (_Float16)(acc[nt][r2] + bias);
        }
    }
}

// layer-0 node GEMM with IN-KERNEL fp32->fp16 fragment conversion from w0.
__device__ __forceinline__ void node_tile0(const float* __restrict__ X,
                                           const float* __restrict__ w0,
                                           const float* __restrict__ b0,
                                           _Float16* __restrict__ out, int bid) {
    const int NK = 4;
    const int Kd = 128;
    int t = threadIdx.x;
    int wave = t >> 6, lane = t & 63;
    int q = lane >> 4, mn = lane & 15;
    int m0 = (bid % 63) * 16;
    int n0 = (bid / 63) * 128 + wave * 32;
    int slice = (bid / 63) * 4 + wave;
    int rr = m0 + mn;
    if (rr >= NN) rr = NN - 1;

    half8 afa[NK];
    half8 bfa[NK][2];
#pragma unroll
    for (int kk = 0; kk < NK; kk++) {
        int ka = kk * 32 + q * 8;
        const float* p = X + (size_t)rr * Kd + ka;
        floatx4 x0 = *(const floatx4*)p;
        floatx4 x1 = *(const floatx4*)(p + 4);
        half8 aa;
#pragma unroll
        for (int j = 0; j < 4; j++) { aa[j] = (_Float16)x0[j]; aa[4 + j] = (_Float16)x1[j]; }
        afa[kk] = aa;
#pragma unroll
        for (int nt = 0; nt < 2; nt++) {
            int n = slice * 32 + nt * 16 + mn;
            int k = kk * 32 + q * 8;
            half8 bb;
            if (n < 256) {
                const float* pa = w0 + (size_t)n * 256 + k;
                floatx4 a0 = *(const floatx4*)pa;
                floatx4 a1 = *(const floatx4*)(pa + 4);
                floatx4 c0 = *(const floatx4*)(pa + 128);
                floatx4 c1 = *(const floatx4*)(pa + 132);
#pragma unroll
                for (int j = 0; j < 4; j++) {
                    bb[j] = (_Float16)(a0[j] - c0[j]);
                    bb[4 + j] = (_Float16)(a1[j] - c1[j]);
                }
            } else {
                const float* pb = w0 + (size_t)(n - 256) * 256 + 128 + k;
                floatx4 c0 = *(const floatx4*)pb;
                floatx4 c1 = *(const floatx4*)(pb + 4);
#pragma unroll
                for (int j = 0; j < 4; j++) {
                    bb[j] = (_Float16)c0[j];
                    bb[4 + j] = (_Float16)c1[j];
                }
            }
            bfa[kk][nt] = bb;
        }
    }
    floatx4 acc[2] = {};
#pragma unroll
    for (int kk = 0; kk < NK; kk++) {
        acc[0] = __builtin_amdgcn_mfma_f32_16x16x32_f16(afa[kk], bfa[kk][0], acc[0], 0, 0, 0);
        acc[1] = __builtin_amdgcn_mfma_f32_16x16x32_f16(afa[kk], bfa[kk][1], acc[1], 0, 0, 0);
    }
#pragma unroll
    for (int nt = 0; nt < 2; nt++) {
        int col = n0 + nt * 16 + mn;
        float bias = (col < 256) ? b0[col] : 0.f;
#pragma unroll
        for (int r2 = 0; r2 < 4; r2++) {
            int orow = m0 + q * 4 + r2;
            if (orow < NN)
                out[(size_t)orow * 512 + col] = (_Float16)(acc[nt][r2] + bias);
        }
    }
}

// ONE pre dispatch: hist (16 private regions) || layer-0 node GEMM || chores.
__global__ __launch_bounds__(256) void k_pre1(PrepArgs pa,
                                              const int* __restrict__ ei,
                                              const float* __restrict__ X,
                                              const float* __restrict__ b0_0,
                                              _Float16* __restrict__ node_ab,
                                              _Float16* wnode, _Float16* w2h,
                                              int* cnts16, int* cursor,
                                              float* agg0, float* dout) {
    int bid = blockIdx.x;
    int t = threadIdx.x;
    if (bid < 16) {
        int* my = cnts16 + bid * 1024;
        for (int i = t; i < 1024; i += 256) my[i] = 0;
        __syncthreads();
        for (int e = bid * 256 + t; e < NE; e += 16 * 256)
            atomicAdd(&my[ei[NE + e] & 1023], 1);
    } else if (bid < 16 + 252) {
        node_tile0(X, pa.w0[0], b0_0, node_ab, bid - 16);
    } else {
        int gtid = (bid - 268) * 256 + t;
        int gs = 256 * 256;
        for (int i = gtid; i < 1024; i += gs) cursor[i] = 0;
        for (int l = 1; l < 5; l++) {
            const float* w0 = pa.w0[l];
            _Float16* wn = wnode + l * 131072;
            for (int i = gtid; i < 131072; i += gs) {
                int j = i & 7;
                int lane = (i >> 3) & 63;
                int nt = (i >> 9) & 1;
                int kk = (i >> 10) & 7;
                int slice = i >> 13;
                int mn = lane & 15, q = lane >> 4;
                int n = slice * 32 + nt * 16 + mn;
                int k = kk * 32 + q * 8 + j;
                float v = (n < 256) ? (w0[n * 512 + k] - w0[n * 512 + 256 + k])
                                    : w0[(n - 256) * 512 + 256 + k];
                wn[i] = (_Float16)v;
            }
        }
        for (int l = 0; l < 5; l++) {
            const float* w1 = pa.w1[l];
            _Float16* w2 = w2h + l * 65536;
            for (int i = gtid; i < 65536; i += gs) {
                int j = i & 7;
                int lane = (i >> 3) & 63;
                int nt = (i >> 9) & 3;
                int kk = (i >> 11) & 7;
                int ws = (i >> 14) & 3;
                int mn = lane & 15, q = lane >> 4;
                int row = ws * 64 + nt * 16 + mn;
                int col = kk * 32 + q * 8 + j;
                w2[i] = (_Float16)w1[row * 256 + col];
            }
        }
        floatx4 z = {0.f, 0.f, 0.f, 0.f};
        floatx4* p4 = (floatx4*)agg0;
        for (int i = gtid; i < 4 * NN * HH / 4; i += gs) p4[i] = z;
        floatx4* o4 = (floatx4*)dout;
        for (int i = gtid; i < NN * HH / 4; i += gs) o4[i] = z;
    }
}

// Replicated scan (sums 16 hist regions) + counting-sort scatter (src only).
// Block 0 additionally builds the chunk table: one int4 {dst, start, len,
// sole} per (dst, <=64 edges) chunk; tail entries zeroed (len=0).
__global__ __launch_bounds__(256) void k_scatter2(const int* __restrict__ ei,
                                                  const int* __restrict__ cnts16,
                                                  int* __restrict__ cursor,
                                                  int* __restrict__ ssrc,
                                                  int4* __restrict__ table) {
    __shared__ int sbase[1024];
    __shared__ int ssum[256];
    __shared__ int schk[256];
    int t = threadIdx.x;
    int base = t * 4;
    int c4[4]; int sum = 0;
#pragma unroll
    for (int j = 0; j < 4; j++) {
        int c = 0;
#pragma unroll
        for (int b = 0; b < 16; b++) c += cnts16[b * 1024 + base + j];
        c4[j] = c; sum += c;
    }
    ssum[t] = sum;
    // chunk counts (second scan array filled before scans run)
    int ch4[4]; int csum = 0;
#pragma unroll
    for (int j = 0; j < 4; j++) { ch4[j] = (c4[j] + 63) >> 6; csum += ch4[j]; }
    schk[t] = csum;
    __syncthreads();
    for (int d = 1; d < 256; d <<= 1) {
        int v1 = (t >= d) ? ssum[t - d] : 0;
        int v2 = (t >= d) ? schk[t - d] : 0;
        __syncthreads();
        ssum[t] += v1;
        schk[t] += v2;
        __syncthreads();
    }
    int run = (t > 0) ? ssum[t - 1] : 0;
#pragma unroll
    for (int j = 0; j < 4; j++) { sbase[base + j] = run; run += c4[j]; }
    __syncthreads();
    if (blockIdx.x == 0) {
        int crun = (t > 0) ? schk[t - 1] : 0;
#pragma unroll
        for (int j = 0; j < 4; j++) {
            int d = base + j, c = c4[j], st = sbase[base + j], nc = ch4[j];
            for (int k = 0; k < nc; k++) {
                int len = c - k * 64; if (len > 64) len = 64;
                table[crun + k] = make_int4(d, st + k * 64, len, nc == 1 ? 1 : 0);
            }
            crun += nc;
        }
        int nch = schk[255];
        for (int i = nch + t; i < 2048; i += 256) table[i] = make_int4(0, 0, 0, 0);
    }
    for (int e = blockIdx.x * 256 + t; e < NE; e += gridDim.x * 256) {
        int s = ei[e] & 1023, d = ei[NE + e] & 1023;
        int pos = sbase[d] + atomicAdd(&cursor[d], 1);
        if (pos < NE) ssrc[pos] = s;
    }
}

// pure node GEMM layer l+1 (reads agg_in), 252 blocks
__global__ __launch_bounds__(256) void k_node(const float* __restrict__ agg_in,
                                              const _Float16* __restrict__ Wn,
                                              const float* __restrict__ b0,
                                              _Float16* __restrict__ out) {
    node_tile<8>(agg_in, Wn, b0, out, blockIdx.x);
}

// ONE dst chunk per block (<=64 edges, dst uniform). Coalesced staging:
// a-row loaded once per lane; b rows gathered 512-B-coalesced; pad rows -> 0.
// MFMA vs fragment-ordered W2 -> acc[4][4]; masked reg-max + 2 shfl_xor ->
// relu(max+bias); sole chunk: plain coalesced store; split: atomicMax.
__global__ __launch_bounds__(256, 4) void edge_gemm3(const _Float16* __restrict__ node_ab,
                          const int* __restrict__ ssrc,
                          const int4* __restrict__ table,
                          const _Float16* __restrict__ W2,
                          const float* __restrict__ b2,
                          float* __restrict__ agg) {
    __shared__ _Float16 h1[64 * 256];
    __shared__ int ssd[64];
    int4 ck = table[blockIdx.x];
    int len = ck.z;
    if (len == 0) return;
    int dst = ck.x, start = ck.y, sole = ck.w;
    int t = threadIdx.x;
    int wave = t >> 6, lane = t & 63;
    int q = lane >> 4, mn = lane & 15;
    const _Float16* W2w = W2 + wave * 16384;

    if (t < 64) ssd[t] = (t < len) ? ssrc[start + t] : 0;
    __syncthreads();
    {
        int s = lane & 31;       // 16-B slot within the 256-half half-row
        int rh = lane >> 5;
        half8 av = *(const half8*)(node_ab + (size_t)dst * 512 + s * 8);  // once
#pragma unroll
        for (int it = 0; it < 8; it++) {
            int row = it * 8 + wave * 2 + rh;          // bijective over 0..63
            half8 hv = {};
            if (row < len) {
                int sn = ssd[row];
                half8 bv = *(const half8*)(node_ab + (size_t)sn * 512 + 256 + s * 8);
                hv = av + bv;
#pragma unroll
                for (int j = 0; j < 8; j++) hv[j] = hv[j] > (_Float16)0 ? hv[j] : (_Float16)0;
            }
            int p = (s & ~7) | ((s ^ row) & 7);        // XOR swizzle, c = s
            *(half8*)(&h1[row * 256 + p * 8]) = hv;
        }
    }
    __syncthreads();

    floatx4 acc[4][4] = {};
#pragma unroll
    for (int kk = 0; kk < 8; kk++) {
        half8 bf[4];
#pragma unroll
        for (int nt = 0; nt < 4; nt++)
            bf[nt] = *(const half8*)(W2w + (kk * 4 + nt) * 512 + lane * 8);  // coalesced
        half8 af[4];
#pragma unroll
        for (int mt = 0; mt < 4; mt++) {
            int r = mt * 16 + mn;
            int c = kk * 4 + q;
            int p = (c & ~7) | ((c ^ r) & 7);
            af[mt] = *(const half8*)(&h1[r * 256 + p * 8]);
        }
#pragma unroll
        for (int mt = 0; mt < 4; mt++)
#pragma unroll
            for (int nt = 0; nt < 4; nt++)
                acc[mt][nt] = __builtin_amdgcn_mfma_f32_16x16x32_f16(af[mt], bf[nt], acc[mt][nt], 0, 0, 0);
    }

    // masked per-thread max over valid rows, then reduce across the 4 q-lanes
    float m[4] = {-3.0e38f, -3.0e38f, -3.0e38f, -3.0e38f};
#pragma unroll
    for (int mt = 0; mt < 4; mt++) {
#pragma unroll
        for (int r2 = 0; r2 < 4; r2++) {
            int row = mt * 16 + q * 4 + r2;
            if (row < len) {
#pragma unroll
                for (int nt = 0; nt < 4; nt++) m[nt] = fmaxf(m[nt], acc[mt][nt][r2]);
            }
        }
    }
#pragma unroll
    for (int nt = 0; nt < 4; nt++) {
        m[nt] = fmaxf(m[nt], __shfl_xor(m[nt], 16, 64));
        m[nt] = fmaxf(m[nt], __shfl_xor(m[nt], 32, 64));
    }
    // lane writes col = wave*64 + q*16 + mn  (256 coalesced cols per block)
    float v = (q == 0) ? m[0] : (q == 1) ? m[1] : (q == 2) ? m[2] : m[3];
    int col = wave * 64 + q * 16 + mn;
    v = v + b2[col];
    v = v > 0.f ? v : 0.f;
    float* p = agg + (size_t)dst * HH + col;
    if (sole) {
        *p = v;                                        // block-exclusive row
    } else if (v > 0.f) {
        atomicMax((unsigned int*)p, __float_as_uint(v));  // agg pre-zeroed
    }
}

extern "C" void kernel_launch(void* const* d_in, const int* in_sizes, int n_in,
                              void* d_out, int out_size, void* d_ws, size_t ws_size,
                              hipStream_t stream) {
    const float* x = (const float*)d_in[0];
    const int* ei = (const int*)d_in[1];  // int32 per harness contract
    PrepArgs pa;
    const float* b0s[5];
    const float* b1s[5];
    for (int l = 0; l < 5; l++) {
        pa.w0[l] = (const float*)d_in[2 + 4 * l];
        b0s[l] = (const float*)d_in[3 + 4 * l];
        pa.w1[l] = (const float*)d_in[4 + 4 * l];
        b1s[l] = (const float*)d_in[5 + 4 * l];
    }

    int* ssrc = (int*)d_ws;                              // 64000 ints
    int* cnts16 = ssrc + NE;                             // 16 x 1024 ints
    int* cursor = cnts16 + 16 * 1024;                    // 1024 ints
    int4* table = (int4*)(cursor + 1024);                // 2048 int4 (32 KB)
    _Float16* node_ab = (_Float16*)(table + 2048);       // [1024][512] fp16, 1 MB
    float* agg0 = (float*)(node_ab + 1024 * 512);        // 4 x 1 MB (contiguous)
    float* agg1 = agg0 + NN * HH;
    float* agg2 = agg1 + NN * HH;
    float* agg3 = agg2 + NN * HH;
    _Float16* wnode = (_Float16*)(agg3 + NN * HH);       // 5 x 131072 halfs (slot 0 unused)
    _Float16* w2h = wnode + 5 * 131072;                  // 5 x 65536 halfs

    hipLaunchKernelGGL(k_pre1, dim3(524), dim3(256), 0, stream,
                       pa, ei, x, b0s[0], node_ab, wnode, w2h,
                       cnts16, cursor, agg0, (float*)d_out);
    hipLaunchKernelGGL(k_scatter2, dim3(NE / 256), dim3(256), 0, stream,
                       ei, cnts16, cursor, ssrc, table);

    float* aggs[5] = {agg0, agg1, agg2, agg3, (float*)d_out};
    for (int l = 0; l < 5; l++) {
        hipLaunchKernelGGL(edge_gemm3, dim3(2048), dim3(256), 0, stream,
                           node_ab, ssrc, table, w2h + (size_t)l * 65536, b1s[l], aggs[l]);
        if (l < 4)
            hipLaunchKernelGGL(k_node, dim3(252), dim3(256), 0, stream,
                               aggs[l], wnode + (size_t)(l + 1) * 131072, b0s[l + 1], node_ab);
    }
}